// Round 1
// baseline (4322.670 us; speedup 1.0000x reference)
//
#include <hip/hip_runtime.h>

// ---------------------------------------------------------------------------
// CANE FeatureEmbedding, algebraically simplified:
//   out[:,  0: 64] = relu(x @ W_ego.T + b_ego)
//   out[:, 64: 96] = e_agg[i]            = sum_{e:row=i} relu(ea[e] @ W_edge.T + b_edge)
//   out[:, 96:128] = dinv[i] * sum_{e:row=i} e_agg[col[e]]
//   out[:,128:224] = relu( sqrt(deg[i])*(x[i] @ W_px.T + b_peer)
//                          + dinv[i] * (sum_{e:row=i} ea[e]) @ W_pe.T )
// where dinv = deg^-0.5 (0 if deg==0). The x[row] gather/scatter collapses
// because gather index == scatter index; nv factors out of all segment sums.
// ---------------------------------------------------------------------------

__global__ void k_deg(const int* __restrict__ row, float* __restrict__ deg, int E) {
    int e = blockIdx.x * blockDim.x + threadIdx.x;
    if (e < E) atomicAdd(&deg[row[e]], 1.0f);
}

// Per edge: h_e = relu(W_edge @ ea + b_edge)  -> atomic into combo[r][0:32]
//           raw ea                            -> atomic into combo[r][32:64]
__global__ __launch_bounds__(256) void k_edge(
    const float* __restrict__ ea, const int* __restrict__ row,
    const float* __restrict__ W_edge, const float* __restrict__ b_edge,
    float* __restrict__ combo, int E)
{
    int e = blockIdx.x * blockDim.x + threadIdx.x;
    if (e >= E) return;
    float a[32];
    const float4* ea4 = reinterpret_cast<const float4*>(ea + (size_t)e * 32);
#pragma unroll
    for (int k = 0; k < 8; ++k) {
        float4 v = ea4[k];
        a[4*k+0] = v.x; a[4*k+1] = v.y; a[4*k+2] = v.z; a[4*k+3] = v.w;
    }
    int r = row[e];
    float* dst = combo + (size_t)r * 64;
#pragma unroll
    for (int j = 0; j < 32; ++j) {
        float acc = b_edge[j];          // uniform -> scalar load
#pragma unroll
        for (int k = 0; k < 32; ++k)
            acc = fmaf(W_edge[j * 32 + k], a[k], acc);   // uniform weights -> s_load
        atomicAdd(&dst[j], fmaxf(acc, 0.0f));
    }
#pragma unroll
    for (int j = 0; j < 32; ++j)
        atomicAdd(&dst[32 + j], a[j]);
}

// Per edge: emm[row[e]] += e_agg[col[e]]  (dinv applied later per node)
__global__ __launch_bounds__(256) void k_mm(
    const int* __restrict__ col, const int* __restrict__ row,
    const float* __restrict__ combo, float* __restrict__ emm, int E)
{
    int e = blockIdx.x * blockDim.x + threadIdx.x;
    if (e >= E) return;
    int r = row[e], c = col[e];
    const float4* src = reinterpret_cast<const float4*>(combo + (size_t)c * 64);
    float* dst = emm + (size_t)r * 32;
#pragma unroll
    for (int q = 0; q < 8; ++q) {
        float4 v = src[q];
        atomicAdd(&dst[4*q+0], v.x);
        atomicAdd(&dst[4*q+1], v.y);
        atomicAdd(&dst[4*q+2], v.z);
        atomicAdd(&dst[4*q+3], v.w);
    }
}

// Per node: ego GEMV (64x128) + copy e_agg + scale emm by dinv
__global__ __launch_bounds__(64) void k_ego(
    const float* __restrict__ x, const float* __restrict__ W_ego,
    const float* __restrict__ b_ego, const float* __restrict__ combo,
    const float* __restrict__ emm, const float* __restrict__ deg,
    float* __restrict__ out, int N)
{
    int i = blockIdx.x * blockDim.x + threadIdx.x;
    if (i >= N) return;
    float acc[64];
#pragma unroll
    for (int j = 0; j < 64; ++j) acc[j] = b_ego[j];
    const float4* xr = reinterpret_cast<const float4*>(x + (size_t)i * 128);
    for (int kc = 0; kc < 32; ++kc) {
        float4 xv = xr[kc];
#pragma unroll
        for (int j = 0; j < 64; ++j) {
            const int wb = j * 128 + kc * 4;
            acc[j] = fmaf(W_ego[wb+0], xv.x, acc[j]);
            acc[j] = fmaf(W_ego[wb+1], xv.y, acc[j]);
            acc[j] = fmaf(W_ego[wb+2], xv.z, acc[j]);
            acc[j] = fmaf(W_ego[wb+3], xv.w, acc[j]);
        }
    }
    float* o = out + (size_t)i * 224;
#pragma unroll
    for (int j = 0; j < 64; ++j) o[j] = fmaxf(acc[j], 0.0f);

    float d = deg[i];
    float dinv = d > 0.0f ? (1.0f / sqrtf(d)) : 0.0f;
    const float* cb = combo + (size_t)i * 64;
    const float* em = emm + (size_t)i * 32;
#pragma unroll
    for (int j = 0; j < 32; ++j) o[64 + j] = cb[j];
#pragma unroll
    for (int j = 0; j < 32; ++j) o[96 + j] = dinv * em[j];
}

// Per node: peer GEMV: relu( sqrt(deg)*(W_px@x + b_peer) + dinv*(W_pe@sum_ea) )
__global__ __launch_bounds__(64) void k_peer(
    const float* __restrict__ x, const float* __restrict__ W_peer,
    const float* __restrict__ b_peer, const float* __restrict__ combo,
    const float* __restrict__ deg, float* __restrict__ out, int N)
{
    int i = blockIdx.x * blockDim.x + threadIdx.x;
    if (i >= N) return;
    float acc[96];
#pragma unroll
    for (int j = 0; j < 96; ++j) acc[j] = 0.0f;
    const float4* xr = reinterpret_cast<const float4*>(x + (size_t)i * 128);
    for (int kc = 0; kc < 32; ++kc) {
        float4 xv = xr[kc];
#pragma unroll
        for (int j = 0; j < 96; ++j) {
            const int wb = j * 160 + kc * 4;
            acc[j] = fmaf(W_peer[wb+0], xv.x, acc[j]);
            acc[j] = fmaf(W_peer[wb+1], xv.y, acc[j]);
            acc[j] = fmaf(W_peer[wb+2], xv.z, acc[j]);
            acc[j] = fmaf(W_peer[wb+3], xv.w, acc[j]);
        }
    }
    float d = deg[i];
    float sd = d > 0.0f ? sqrtf(d) : 0.0f;
    float dinv = d > 0.0f ? (1.0f / sqrtf(d)) : 0.0f;
#pragma unroll
    for (int j = 0; j < 96; ++j) acc[j] = sd * (acc[j] + b_peer[j]);

    const float4* er = reinterpret_cast<const float4*>(combo + (size_t)i * 64 + 32);
    for (int kc = 0; kc < 8; ++kc) {
        float4 av = er[kc];
        av.x *= dinv; av.y *= dinv; av.z *= dinv; av.w *= dinv;
#pragma unroll
        for (int j = 0; j < 96; ++j) {
            const int wb = j * 160 + 128 + kc * 4;
            acc[j] = fmaf(W_peer[wb+0], av.x, acc[j]);
            acc[j] = fmaf(W_peer[wb+1], av.y, acc[j]);
            acc[j] = fmaf(W_peer[wb+2], av.z, acc[j]);
            acc[j] = fmaf(W_peer[wb+3], av.w, acc[j]);
        }
    }
    float* o = out + (size_t)i * 224 + 128;
#pragma unroll
    for (int j = 0; j < 96; ++j) o[j] = fmaxf(acc[j], 0.0f);
}

extern "C" void kernel_launch(void* const* d_in, const int* in_sizes, int n_in,
                              void* d_out, int out_size, void* d_ws, size_t ws_size,
                              hipStream_t stream)
{
    const float* x      = (const float*)d_in[0];
    const float* ea     = (const float*)d_in[1];
    const float* W_peer = (const float*)d_in[2];
    const float* b_peer = (const float*)d_in[3];
    const float* W_ego  = (const float*)d_in[4];
    const float* b_ego  = (const float*)d_in[5];
    const float* W_edge = (const float*)d_in[6];
    const float* b_edge = (const float*)d_in[7];
    const int*   ei     = (const int*)d_in[8];

    const int N = in_sizes[0] / 128;
    const int E = in_sizes[8] / 2;
    const int* col = ei;        // edge_index[0]
    const int* row = ei + E;    // edge_index[1]

    float* deg   = (float*)d_ws;                 // [N]
    float* combo = deg + N;                      // [N][64]: 0:32 e_agg, 32:64 sum_ea
    float* emm   = combo + (size_t)N * 64;       // [N][32]
    float* out   = (float*)d_out;

    hipMemsetAsync(d_ws, 0, (size_t)N * 97 * sizeof(float), stream);

    const int TB = 256;
    k_deg <<<(E + TB - 1) / TB, TB, 0, stream>>>(row, deg, E);
    k_edge<<<(E + TB - 1) / TB, TB, 0, stream>>>(ea, row, W_edge, b_edge, combo, E);
    k_mm  <<<(E + TB - 1) / TB, TB, 0, stream>>>(col, row, combo, emm, E);
    k_ego <<<(N + 63) / 64, 64, 0, stream>>>(x, W_ego, b_ego, combo, emm, deg, out, N);
    k_peer<<<(N + 63) / 64, 64, 0, stream>>>(x, W_peer, b_peer, combo, deg, out, N);
}

// Round 2
// 640.995 us; speedup vs baseline: 6.7437x; 6.7437x over previous
//
#include <hip/hip_runtime.h>

// ---------------------------------------------------------------------------
// CSR-based rewrite. Algebra (unchanged from round 1):
//   out[:,  0: 64] = relu(x @ W_ego.T + b_ego)
//   out[:, 64: 96] = e_agg[i]   = sum_{e:row=i} relu(ea[e] @ W_edge.T + b_edge)
//   out[:, 96:128] = dinv[i] * sum_{e:row=i} e_agg[col[e]]
//   out[:,128:224] = relu( sqrt(deg)*(x @ W_px.T + b_peer) + dinv*(sum_ea @ W_pe.T) )
// New: build CSR (deg histogram -> scan -> scatter, 1 int atomic/edge), then
// per-node wave aggregation with register accumulators -> NO float atomics.
// ---------------------------------------------------------------------------

__global__ __launch_bounds__(256) void k_hist(const int* __restrict__ row,
                                              int* __restrict__ deg, int E) {
    int e = blockIdx.x * blockDim.x + threadIdx.x;
    if (e < E) atomicAdd(&deg[row[e]], 1);
}

__global__ __launch_bounds__(256) void k_scan_partial(const int* __restrict__ deg,
                                                      int* __restrict__ bsum, int N) {
    __shared__ int sh[256];
    int base = blockIdx.x * 1024 + threadIdx.x * 4;
    int s = 0;
#pragma unroll
    for (int q = 0; q < 4; ++q) { int i = base + q; if (i < N) s += deg[i]; }
    sh[threadIdx.x] = s;
    __syncthreads();
    for (int off = 128; off > 0; off >>= 1) {
        if (threadIdx.x < off) sh[threadIdx.x] += sh[threadIdx.x + off];
        __syncthreads();
    }
    if (threadIdx.x == 0) bsum[blockIdx.x] = sh[0];
}

__global__ void k_scan_mid(const int* __restrict__ bsum, int* __restrict__ boff,
                           int* __restrict__ off, int NB, int N) {
    if (threadIdx.x == 0 && blockIdx.x == 0) {
        int acc = 0;
        for (int b = 0; b < NB; ++b) { boff[b] = acc; acc += bsum[b]; }
        off[N] = acc;   // == E
    }
}

__global__ __launch_bounds__(256) void k_scan_final(const int* __restrict__ deg,
                                                    const int* __restrict__ boff,
                                                    int* __restrict__ off,
                                                    int* __restrict__ cursor, int N) {
    __shared__ int sh[256];
    int t = threadIdx.x;
    int base = blockIdx.x * 1024 + t * 4;
    int v[4];
#pragma unroll
    for (int q = 0; q < 4; ++q) v[q] = (base + q < N) ? deg[base + q] : 0;
    int ts = v[0] + v[1] + v[2] + v[3];
    sh[t] = ts;
    __syncthreads();
    int incl = ts;
    for (int d = 1; d < 256; d <<= 1) {
        int val = (t >= d) ? sh[t - d] : 0;
        __syncthreads();
        incl += val;
        sh[t] = incl;
        __syncthreads();
    }
    int running = boff[blockIdx.x] + incl - ts;
#pragma unroll
    for (int q = 0; q < 4; ++q) {
        int i = base + q;
        if (i < N) { off[i] = running; cursor[i] = running; running += v[q]; }
    }
}

__global__ __launch_bounds__(256) void k_scatter(const int* __restrict__ row,
                                                 const int* __restrict__ col,
                                                 int* __restrict__ cursor,
                                                 int* __restrict__ eids,
                                                 int* __restrict__ colsort, int E) {
    int e = blockIdx.x * blockDim.x + threadIdx.x;
    if (e >= E) return;
    int pos = atomicAdd(&cursor[row[e]], 1);
    eids[pos] = e;
    colsort[pos] = col[e];
}

// One wave per node. Half-wave (32 lanes) per edge; lane j = feature j.
// h_e GEMV via 32 segment-broadcast shuffles (LDS pipe || VMEM gather pipe).
__global__ __launch_bounds__(256) void k_agg(
    const float* __restrict__ ea, const int* __restrict__ eids,
    const int* __restrict__ off,
    const float* __restrict__ W_edge, const float* __restrict__ b_edge,
    float* __restrict__ combo, float* __restrict__ out, int N)
{
    int wid  = (blockIdx.x * blockDim.x + threadIdx.x) >> 6;   // node
    int lane = threadIdx.x & 63;
    if (wid >= N) return;
    int j = lane & 31;
    float wrow[32];
#pragma unroll
    for (int k = 0; k < 32; ++k) wrow[k] = W_edge[j * 32 + k];
    float bj = b_edge[j];

    int s = off[wid], e = off[wid + 1];
    float acc_he = 0.f, acc_ea = 0.f;
    for (int t0 = s; t0 < e; t0 += 2) {            // uniform loop: shfl all-active
        int t = t0 + (lane >> 5);
        float v = 0.f;
        if (t < e) v = ea[(size_t)eids[t] * 32 + j];
        acc_ea += v;
        float h = bj;
#pragma unroll
        for (int k = 0; k < 32; ++k)
            h = fmaf(wrow[k], __shfl(v, k, 32), h);
        if (t < e) acc_he += fmaxf(h, 0.f);
    }
    acc_he += __shfl_xor(acc_he, 32);
    acc_ea += __shfl_xor(acc_ea, 32);
    if (lane < 32) {
        combo[(size_t)wid * 64 + j]      = acc_he;   // e_agg (phase-3 gather src)
        combo[(size_t)wid * 64 + 32 + j] = acc_ea;   // sum_ea (k_peer src)
        out[(size_t)wid * 224 + 64 + j]  = acc_he;
    }
}

// out[:,96:128] = dinv[i] * sum_{e:row=i} e_agg[col[e]]
__global__ __launch_bounds__(256) void k_mmagg(
    const int* __restrict__ colsort, const int* __restrict__ off,
    const float* __restrict__ combo, float* __restrict__ out, int N)
{
    int wid  = (blockIdx.x * blockDim.x + threadIdx.x) >> 6;
    int lane = threadIdx.x & 63;
    if (wid >= N) return;
    int j = lane & 31;
    int s = off[wid], e = off[wid + 1];
    float acc = 0.f;
    for (int t0 = s; t0 < e; t0 += 2) {
        int t = t0 + (lane >> 5);
        if (t < e) acc += combo[(size_t)colsort[t] * 64 + j];
    }
    acc += __shfl_xor(acc, 32);
    int dg = e - s;
    float dinv = dg > 0 ? rsqrtf((float)dg) : 0.f;
    if (lane < 32) out[(size_t)wid * 224 + 96 + j] = dinv * acc;
}

__global__ __launch_bounds__(256) void k_ego(
    const float* __restrict__ x, const float* __restrict__ W_ego,
    const float* __restrict__ b_ego, float* __restrict__ out, int N)
{
    int i = blockIdx.x * blockDim.x + threadIdx.x;
    if (i >= N) return;
    float acc[64];
#pragma unroll
    for (int j = 0; j < 64; ++j) acc[j] = b_ego[j];
    const float4* xr = reinterpret_cast<const float4*>(x + (size_t)i * 128);
    for (int kc = 0; kc < 32; ++kc) {
        float4 xv = xr[kc];
#pragma unroll
        for (int j = 0; j < 64; ++j) {
            const int wb = j * 128 + kc * 4;
            acc[j] = fmaf(W_ego[wb+0], xv.x, acc[j]);
            acc[j] = fmaf(W_ego[wb+1], xv.y, acc[j]);
            acc[j] = fmaf(W_ego[wb+2], xv.z, acc[j]);
            acc[j] = fmaf(W_ego[wb+3], xv.w, acc[j]);
        }
    }
    float* o = out + (size_t)i * 224;
#pragma unroll
    for (int j = 0; j < 64; ++j) o[j] = fmaxf(acc[j], 0.0f);
}

__global__ __launch_bounds__(256) void k_peer(
    const float* __restrict__ x, const float* __restrict__ W_peer,
    const float* __restrict__ b_peer, const float* __restrict__ combo,
    const int* __restrict__ off, float* __restrict__ out, int N)
{
    int i = blockIdx.x * blockDim.x + threadIdx.x;
    if (i >= N) return;
    float acc[96];
#pragma unroll
    for (int j = 0; j < 96; ++j) acc[j] = 0.0f;
    const float4* xr = reinterpret_cast<const float4*>(x + (size_t)i * 128);
    for (int kc = 0; kc < 32; ++kc) {
        float4 xv = xr[kc];
#pragma unroll
        for (int j = 0; j < 96; ++j) {
            const int wb = j * 160 + kc * 4;
            acc[j] = fmaf(W_peer[wb+0], xv.x, acc[j]);
            acc[j] = fmaf(W_peer[wb+1], xv.y, acc[j]);
            acc[j] = fmaf(W_peer[wb+2], xv.z, acc[j]);
            acc[j] = fmaf(W_peer[wb+3], xv.w, acc[j]);
        }
    }
    int dg = off[i + 1] - off[i];
    float sd   = dg > 0 ? sqrtf((float)dg)  : 0.f;
    float dinv = dg > 0 ? rsqrtf((float)dg) : 0.f;
#pragma unroll
    for (int j = 0; j < 96; ++j) acc[j] = sd * (acc[j] + b_peer[j]);

    const float4* er = reinterpret_cast<const float4*>(combo + (size_t)i * 64 + 32);
    for (int kc = 0; kc < 8; ++kc) {
        float4 av = er[kc];
        av.x *= dinv; av.y *= dinv; av.z *= dinv; av.w *= dinv;
#pragma unroll
        for (int j = 0; j < 96; ++j) {
            const int wb = j * 160 + 128 + kc * 4;
            acc[j] = fmaf(W_peer[wb+0], av.x, acc[j]);
            acc[j] = fmaf(W_peer[wb+1], av.y, acc[j]);
            acc[j] = fmaf(W_peer[wb+2], av.z, acc[j]);
            acc[j] = fmaf(W_peer[wb+3], av.w, acc[j]);
        }
    }
    float* o = out + (size_t)i * 224 + 128;
#pragma unroll
    for (int j = 0; j < 96; ++j) o[j] = fmaxf(acc[j], 0.0f);
}

extern "C" void kernel_launch(void* const* d_in, const int* in_sizes, int n_in,
                              void* d_out, int out_size, void* d_ws, size_t ws_size,
                              hipStream_t stream)
{
    const float* x      = (const float*)d_in[0];
    const float* ea     = (const float*)d_in[1];
    const float* W_peer = (const float*)d_in[2];
    const float* b_peer = (const float*)d_in[3];
    const float* W_ego  = (const float*)d_in[4];
    const float* b_ego  = (const float*)d_in[5];
    const float* W_edge = (const float*)d_in[6];
    const float* b_edge = (const float*)d_in[7];
    const int*   ei     = (const int*)d_in[8];

    const int N = in_sizes[0] / 128;
    const int E = in_sizes[8] / 2;
    const int* col = ei;        // edge_index[0]
    const int* row = ei + E;    // edge_index[1]

    // workspace layout (ints then 16B-aligned floats)
    int*  deg_i   = (int*)d_ws;                    // [N]
    int*  off     = deg_i + N;                     // [N+1]
    int*  cursor  = off + (N + 1);                 // [N]
    int*  bsum    = cursor + N;                    // [64]
    int*  boff    = bsum + 64;                     // [64]
    int*  eids    = boff + 64;                     // [E]
    int*  colsort = eids + E;                      // [E]
    size_t fofs   = (size_t)((colsort + E) - (int*)d_ws);
    fofs = (fofs + 3) & ~(size_t)3;                // 16B align
    float* combo  = (float*)d_ws + fofs;           // [N][64]: e_agg | sum_ea
    float* out    = (float*)d_out;

    hipMemsetAsync(deg_i, 0, (size_t)N * sizeof(int), stream);

    const int TB = 256;
    const int NB = (N + 1023) / 1024;
    k_hist        <<<(E + TB - 1) / TB, TB, 0, stream>>>(row, deg_i, E);
    k_scan_partial<<<NB, TB, 0, stream>>>(deg_i, bsum, N);
    k_scan_mid    <<<1, 64, 0, stream>>>(bsum, boff, off, NB, N);
    k_scan_final  <<<NB, TB, 0, stream>>>(deg_i, boff, off, cursor, N);
    k_scatter     <<<(E + TB - 1) / TB, TB, 0, stream>>>(row, col, cursor, eids, colsort, E);

    const int nodes_per_blk = TB / 64;
    const int agg_grid = (N + nodes_per_blk - 1) / nodes_per_blk;
    k_agg  <<<agg_grid, TB, 0, stream>>>(ea, eids, off, W_edge, b_edge, combo, out, N);
    k_mmagg<<<agg_grid, TB, 0, stream>>>(colsort, off, combo, out, N);
    k_ego  <<<(N + TB - 1) / TB, TB, 0, stream>>>(x, W_ego, b_ego, out, N);
    k_peer <<<(N + TB - 1) / TB, TB, 0, stream>>>(x, W_peer, b_peer, combo, off, out, N);
}

// Round 3
// 436.471 us; speedup vs baseline: 9.9037x; 1.4686x over previous
//
#include <hip/hip_runtime.h>

// ---------------------------------------------------------------------------
// CSR build (1 int atomic/edge) + wave-per-node edge aggregation (no float
// atomics) + fused node-level GEMM with LDS node tile:
//   out[:,  0: 64] = relu(x @ W_ego.T + b_ego)
//   out[:, 64: 96] = e_agg[i]   = sum_{e:row=i} relu(ea[e] @ W_edge.T + b_edge)
//   out[:, 96:128] = dinv[i] * sum_{e:row=i} e_agg[col[e]]
//   out[:,128:224] = relu( sd * (W_peer @ [x | sea/deg] + b_peer) )
//     (== relu(sd*(W_px@x+b_peer) + dinv*(W_pe@sea)) since sd/deg = dinv)
// ---------------------------------------------------------------------------

__global__ __launch_bounds__(256) void k_hist(const int* __restrict__ row,
                                              int* __restrict__ deg, int E) {
    int e = blockIdx.x * blockDim.x + threadIdx.x;
    if (e < E) atomicAdd(&deg[row[e]], 1);
}

__global__ __launch_bounds__(256) void k_scan_partial(const int* __restrict__ deg,
                                                      int* __restrict__ bsum, int N) {
    __shared__ int sh[256];
    int base = blockIdx.x * 1024 + threadIdx.x * 4;
    int s = 0;
#pragma unroll
    for (int q = 0; q < 4; ++q) { int i = base + q; if (i < N) s += deg[i]; }
    sh[threadIdx.x] = s;
    __syncthreads();
    for (int off = 128; off > 0; off >>= 1) {
        if (threadIdx.x < off) sh[threadIdx.x] += sh[threadIdx.x + off];
        __syncthreads();
    }
    if (threadIdx.x == 0) bsum[blockIdx.x] = sh[0];
}

__global__ void k_scan_mid(const int* __restrict__ bsum, int* __restrict__ boff,
                           int* __restrict__ off, int NB, int N) {
    if (threadIdx.x == 0 && blockIdx.x == 0) {
        int acc = 0;
        for (int b = 0; b < NB; ++b) { boff[b] = acc; acc += bsum[b]; }
        off[N] = acc;   // == E
    }
}

__global__ __launch_bounds__(256) void k_scan_final(const int* __restrict__ deg,
                                                    const int* __restrict__ boff,
                                                    int* __restrict__ off,
                                                    int* __restrict__ cursor, int N) {
    __shared__ int sh[256];
    int t = threadIdx.x;
    int base = blockIdx.x * 1024 + t * 4;
    int v[4];
#pragma unroll
    for (int q = 0; q < 4; ++q) v[q] = (base + q < N) ? deg[base + q] : 0;
    int ts = v[0] + v[1] + v[2] + v[3];
    sh[t] = ts;
    __syncthreads();
    int incl = ts;
    for (int d = 1; d < 256; d <<= 1) {
        int val = (t >= d) ? sh[t - d] : 0;
        __syncthreads();
        incl += val;
        sh[t] = incl;
        __syncthreads();
    }
    int running = boff[blockIdx.x] + incl - ts;
#pragma unroll
    for (int q = 0; q < 4; ++q) {
        int i = base + q;
        if (i < N) { off[i] = running; cursor[i] = running; running += v[q]; }
    }
}

__global__ __launch_bounds__(256) void k_scatter(const int* __restrict__ row,
                                                 const int* __restrict__ col,
                                                 int* __restrict__ cursor,
                                                 int* __restrict__ eids,
                                                 int* __restrict__ colsort, int E) {
    int e = blockIdx.x * blockDim.x + threadIdx.x;
    if (e >= E) return;
    int pos = atomicAdd(&cursor[row[e]], 1);
    eids[pos] = e;
    colsort[pos] = col[e];
}

// One wave per node. Half-wave (32 lanes) per edge; lane j = feature j.
__global__ __launch_bounds__(256) void k_agg(
    const float* __restrict__ ea, const int* __restrict__ eids,
    const int* __restrict__ off,
    const float* __restrict__ W_edge, const float* __restrict__ b_edge,
    float* __restrict__ combo, float* __restrict__ out, int N)
{
    int wid  = (blockIdx.x * blockDim.x + threadIdx.x) >> 6;   // node
    int lane = threadIdx.x & 63;
    if (wid >= N) return;
    int j = lane & 31;
    float wrow[32];
#pragma unroll
    for (int k = 0; k < 32; ++k) wrow[k] = W_edge[j * 32 + k];
    float bj = b_edge[j];

    int s = off[wid], e = off[wid + 1];
    float acc_he = 0.f, acc_ea = 0.f;
    for (int t0 = s; t0 < e; t0 += 2) {            // uniform loop: shfl all-active
        int t = t0 + (lane >> 5);
        float v = 0.f;
        if (t < e) v = ea[(size_t)eids[t] * 32 + j];
        acc_ea += v;
        float h = bj;
#pragma unroll
        for (int k = 0; k < 32; ++k)
            h = fmaf(wrow[k], __shfl(v, k, 32), h);
        if (t < e) acc_he += fmaxf(h, 0.f);
    }
    acc_he += __shfl_xor(acc_he, 32);
    acc_ea += __shfl_xor(acc_ea, 32);
    if (lane < 32) {
        combo[(size_t)wid * 64 + j]      = acc_he;   // e_agg (mm gather src)
        combo[(size_t)wid * 64 + 32 + j] = acc_ea;   // sum_ea (k_node src)
        out[(size_t)wid * 224 + 64 + j]  = acc_he;
    }
}

// out[:,96:128] = dinv[i] * sum_{e:row=i} e_agg[col[e]]  (8 edges/wave-iter, float4)
__global__ __launch_bounds__(256) void k_mmagg(
    const int* __restrict__ colsort, const int* __restrict__ off,
    const float* __restrict__ combo, float* __restrict__ out, int N)
{
    int wid  = (blockIdx.x * blockDim.x + threadIdx.x) >> 6;
    int lane = threadIdx.x & 63;
    if (wid >= N) return;
    int s = off[wid], e = off[wid + 1];
    int c   = lane & 7;          // float4 slot within 32-feature row
    int sub = lane >> 3;         // edge sub-slot 0..7
    float4 acc = {0.f, 0.f, 0.f, 0.f};
    for (int t0 = s; t0 < e; t0 += 8) {
        int t = t0 + sub;
        if (t < e) {
            float4 v = reinterpret_cast<const float4*>(combo + (size_t)colsort[t] * 64)[c];
            acc.x += v.x; acc.y += v.y; acc.z += v.z; acc.w += v.w;
        }
    }
#pragma unroll
    for (int m = 8; m < 64; m <<= 1) {
        acc.x += __shfl_xor(acc.x, m);
        acc.y += __shfl_xor(acc.y, m);
        acc.z += __shfl_xor(acc.z, m);
        acc.w += __shfl_xor(acc.w, m);
    }
    int dg = e - s;
    float dinv = dg > 0 ? rsqrtf((float)dg) : 0.f;
    if (lane < 8) {
        float4 o4 = {acc.x * dinv, acc.y * dinv, acc.z * dinv, acc.w * dinv};
        reinterpret_cast<float4*>(out + (size_t)wid * 224 + 96)[c] = o4;
    }
}

// Fused ego+peer node GEMM. 64 nodes/block in LDS; wave q owns output quarter q.
// Weight indices wave-uniform (readfirstlane) -> s_load / constant cache.
#define TM 64
__global__ __launch_bounds__(256) void k_node(
    const float* __restrict__ x, const float* __restrict__ combo,
    const int* __restrict__ off,
    const float* __restrict__ W_ego, const float* __restrict__ b_ego,
    const float* __restrict__ W_peer, const float* __restrict__ b_peer,
    float* __restrict__ out, int N)
{
    __shared__ float a[TM][161];   // [x(128) | sea/deg(32) | sd(1)]
    const int tid = threadIdx.x;
    const int nb = blockIdx.x * TM;

    for (int f = tid; f < TM * 32; f += 256) {         // stage x, coalesced
        int n = f >> 5, c = f & 31;
        if (nb + n < N) {
            float4 v = reinterpret_cast<const float4*>(x + (size_t)(nb + n) * 128)[c];
            a[n][c*4+0] = v.x; a[n][c*4+1] = v.y; a[n][c*4+2] = v.z; a[n][c*4+3] = v.w;
        }
    }
    for (int f = tid; f < TM * 8; f += 256) {          // stage sea/deg + sd
        int n = f >> 3, c = f & 7;
        if (nb + n < N) {
            int dg = off[nb + n + 1] - off[nb + n];
            float r = dg > 0 ? 1.0f / (float)dg : 0.0f;
            float4 v = reinterpret_cast<const float4*>(combo + (size_t)(nb + n) * 64 + 32)[c];
            a[n][128 + c*4 + 0] = v.x * r;
            a[n][128 + c*4 + 1] = v.y * r;
            a[n][128 + c*4 + 2] = v.z * r;
            a[n][128 + c*4 + 3] = v.w * r;
            if (c == 0) a[n][160] = dg > 0 ? sqrtf((float)dg) : 0.0f;
        }
    }
    __syncthreads();

    const int lane = tid & 63;                          // node within tile
    const int q = __builtin_amdgcn_readfirstlane(tid >> 6);  // output quarter
    const int node = nb + lane;

    float acc_e[16], acc_p[24];
#pragma unroll
    for (int j = 0; j < 16; ++j) acc_e[j] = 0.f;
#pragma unroll
    for (int j = 0; j < 24; ++j) acc_p[j] = 0.f;

    const float* We = W_ego  + q * 16 * 128;
    const float* Wp = W_peer + q * 24 * 160;

#pragma unroll 4
    for (int k = 0; k < 128; ++k) {
        float av = a[lane][k];
#pragma unroll
        for (int j = 0; j < 16; ++j) acc_e[j] = fmaf(We[j*128 + k], av, acc_e[j]);
#pragma unroll
        for (int j = 0; j < 24; ++j) acc_p[j] = fmaf(Wp[j*160 + k], av, acc_p[j]);
    }
#pragma unroll 4
    for (int k = 128; k < 160; ++k) {
        float av = a[lane][k];
#pragma unroll
        for (int j = 0; j < 24; ++j) acc_p[j] = fmaf(Wp[j*160 + k], av, acc_p[j]);
    }

    if (node >= N) return;
    float sd = a[lane][160];
    float* o = out + (size_t)node * 224;
#pragma unroll
    for (int j = 0; j < 16; ++j)
        o[q*16 + j] = fmaxf(acc_e[j] + b_ego[q*16 + j], 0.f);
#pragma unroll
    for (int j = 0; j < 24; ++j)
        o[128 + q*24 + j] = fmaxf(sd * (acc_p[j] + b_peer[q*24 + j]), 0.f);
}

extern "C" void kernel_launch(void* const* d_in, const int* in_sizes, int n_in,
                              void* d_out, int out_size, void* d_ws, size_t ws_size,
                              hipStream_t stream)
{
    const float* x      = (const float*)d_in[0];
    const float* ea     = (const float*)d_in[1];
    const float* W_peer = (const float*)d_in[2];
    const float* b_peer = (const float*)d_in[3];
    const float* W_ego  = (const float*)d_in[4];
    const float* b_ego  = (const float*)d_in[5];
    const float* W_edge = (const float*)d_in[6];
    const float* b_edge = (const float*)d_in[7];
    const int*   ei     = (const int*)d_in[8];

    const int N = in_sizes[0] / 128;
    const int E = in_sizes[8] / 2;
    const int* col = ei;        // edge_index[0]
    const int* row = ei + E;    // edge_index[1]

    int*  deg_i   = (int*)d_ws;                    // [N]
    int*  off     = deg_i + N;                     // [N+1]
    int*  cursor  = off + (N + 1);                 // [N]
    int*  bsum    = cursor + N;                    // [64]
    int*  boff    = bsum + 64;                     // [64]
    int*  eids    = boff + 64;                     // [E]
    int*  colsort = eids + E;                      // [E]
    size_t fofs   = (size_t)((colsort + E) - (int*)d_ws);
    fofs = (fofs + 3) & ~(size_t)3;                // 16B align
    float* combo  = (float*)d_ws + fofs;           // [N][64]: e_agg | sum_ea
    float* out    = (float*)d_out;

    hipMemsetAsync(deg_i, 0, (size_t)N * sizeof(int), stream);

    const int TB = 256;
    const int NB = (N + 1023) / 1024;
    k_hist        <<<(E + TB - 1) / TB, TB, 0, stream>>>(row, deg_i, E);
    k_scan_partial<<<NB, TB, 0, stream>>>(deg_i, bsum, N);
    k_scan_mid    <<<1, 64, 0, stream>>>(bsum, boff, off, NB, N);
    k_scan_final  <<<NB, TB, 0, stream>>>(deg_i, boff, off, cursor, N);
    k_scatter     <<<(E + TB - 1) / TB, TB, 0, stream>>>(row, col, cursor, eids, colsort, E);

    const int nodes_per_blk = TB / 64;
    const int agg_grid = (N + nodes_per_blk - 1) / nodes_per_blk;
    k_agg  <<<agg_grid, TB, 0, stream>>>(ea, eids, off, W_edge, b_edge, combo, out, N);
    k_mmagg<<<agg_grid, TB, 0, stream>>>(colsort, off, combo, out, N);
    k_node <<<(N + TM - 1) / TM, TB, 0, stream>>>(x, combo, off, W_ego, b_ego,
                                                  W_peer, b_peer, out, N);
}

// Round 4
// 335.362 us; speedup vs baseline: 12.8896x; 1.3015x over previous
//
#include <hip/hip_runtime.h>

// ---------------------------------------------------------------------------
// CSR build (1 int atomic/edge), then ONE fused kernel does edge GEMV +
// segmented per-node aggregation (block-CSR, LDS transpose, no shuffles in
// the matvec, float atomics only at block boundaries):
//   out[:,  0: 64] = relu(x @ W_ego.T + b_ego)
//   out[:, 64: 96] = eagg[i]  = sum_{e:row=i} relu(ea[e] @ W_edge.T + b_edge)
//   out[:, 96:128] = dinv[i] * sum_{e:row=i} eagg[col[e]]
//   out[:,128:224] = relu( sd * (W_peer @ [x | sea/deg] + b_peer) )
// ---------------------------------------------------------------------------

__global__ __launch_bounds__(256) void k_hist(const int* __restrict__ row,
                                              int* __restrict__ deg, int E) {
    int e = blockIdx.x * blockDim.x + threadIdx.x;
    if (e < E) atomicAdd(&deg[row[e]], 1);
}

__global__ __launch_bounds__(256) void k_scan_partial(const int* __restrict__ deg,
                                                      int* __restrict__ bsum, int N) {
    __shared__ int sh[256];
    int base = blockIdx.x * 1024 + threadIdx.x * 4;
    int s = 0;
#pragma unroll
    for (int q = 0; q < 4; ++q) { int i = base + q; if (i < N) s += deg[i]; }
    sh[threadIdx.x] = s;
    __syncthreads();
    for (int off = 128; off > 0; off >>= 1) {
        if (threadIdx.x < off) sh[threadIdx.x] += sh[threadIdx.x + off];
        __syncthreads();
    }
    if (threadIdx.x == 0) bsum[blockIdx.x] = sh[0];
}

__global__ void k_scan_mid(const int* __restrict__ bsum, int* __restrict__ boff,
                           int* __restrict__ off, int NB, int N) {
    if (threadIdx.x == 0 && blockIdx.x == 0) {
        int acc = 0;
        for (int b = 0; b < NB; ++b) { boff[b] = acc; acc += bsum[b]; }
        off[N] = acc;   // == E
    }
}

__global__ __launch_bounds__(256) void k_scan_final(const int* __restrict__ deg,
                                                    const int* __restrict__ boff,
                                                    int* __restrict__ off,
                                                    int* __restrict__ cursor, int N) {
    __shared__ int sh[256];
    int t = threadIdx.x;
    int base = blockIdx.x * 1024 + t * 4;
    int v[4];
#pragma unroll
    for (int q = 0; q < 4; ++q) v[q] = (base + q < N) ? deg[base + q] : 0;
    int ts = v[0] + v[1] + v[2] + v[3];
    sh[t] = ts;
    __syncthreads();
    int incl = ts;
    for (int d = 1; d < 256; d <<= 1) {
        int val = (t >= d) ? sh[t - d] : 0;
        __syncthreads();
        incl += val;
        sh[t] = incl;
        __syncthreads();
    }
    int running = boff[blockIdx.x] + incl - ts;
#pragma unroll
    for (int q = 0; q < 4; ++q) {
        int i = base + q;
        if (i < N) { off[i] = running; cursor[i] = running; running += v[q]; }
    }
}

__global__ __launch_bounds__(256) void k_scatter(const int* __restrict__ row,
                                                 const int* __restrict__ col,
                                                 int* __restrict__ cursor,
                                                 int* __restrict__ eids,
                                                 int* __restrict__ colsort, int E) {
    int e = blockIdx.x * blockDim.x + threadIdx.x;
    if (e >= E) return;
    int pos = atomicAdd(&cursor[row[e]], 1);
    eids[pos] = e;
    colsort[pos] = col[e];
}

__device__ __forceinline__ int find_node(const int* __restrict__ off, int N, int p) {
    // largest n in [0,N-1] with off[n] <= p  (requires p < off[N])
    int lo = 0, hi = N;
    while (hi - lo > 1) { int mid = (lo + hi) >> 1; if (off[mid] <= p) lo = mid; else hi = mid; }
    return lo;
}

// Fused: per-edge GEMV (scalar weights, no shuffles) -> LDS -> segmented sum.
#define BP 128
__global__ __launch_bounds__(BP) void k_fused(
    const float* __restrict__ ea, const int* __restrict__ eids,
    const int* __restrict__ off,
    const float* __restrict__ W_edge, const float* __restrict__ b_edge,
    float* __restrict__ eagg, float* __restrict__ sea, int N, int E)
{
    __shared__ float hs[BP][33];    // +1 pad: write banks (tid+j)%32 -> conflict-free
    __shared__ int eid_s[BP];
    const int tid = threadIdx.x;
    const int P = blockIdx.x * BP;
    const int p = P + tid;

    if (p < E) {
        int e = eids[p];
        eid_s[tid] = e;
        float a[32];
        const float4* r4 = reinterpret_cast<const float4*>(ea + (size_t)e * 32);
#pragma unroll
        for (int q = 0; q < 8; ++q) {
            float4 v = r4[q];
            a[4*q+0]=v.x; a[4*q+1]=v.y; a[4*q+2]=v.z; a[4*q+3]=v.w;
        }
#pragma unroll
        for (int j = 0; j < 32; ++j) {
            float h = b_edge[j];                         // uniform -> SGPR
#pragma unroll
            for (int k = 0; k < 32; ++k)
                h = fmaf(W_edge[j*32+k], a[k], h);       // uniform -> SGPR
            hs[tid][j] = fmaxf(h, 0.f);
        }
    } else {
        eid_s[tid] = 0;
    }
    __syncthreads();

    const int pend = min(P + BP - 1, E - 1);
    const int node_lo = find_node(off, N, P);
    const int node_hi = find_node(off, N, pend);
    const int wv = tid >> 6, lane = tid & 63;
    const int c = lane & 7, sub = lane >> 3;

    for (int n = node_lo + wv; n <= node_hi; n += 2) {
        int s0 = off[n], e0 = off[n+1];
        int s = max(s0, P) - P, e = min(e0, P + BP) - P;
        float h0=0.f,h1=0.f,h2=0.f,h3=0.f;
        float4 ae = {0.f,0.f,0.f,0.f};
        for (int t = s + sub; t < e; t += 8) {
            h0 += hs[t][c*4+0];
            h1 += hs[t][c*4+1];
            h2 += hs[t][c*4+2];
            h3 += hs[t][c*4+3];
            float4 v = reinterpret_cast<const float4*>(ea + (size_t)eid_s[t] * 32)[c];
            ae.x += v.x; ae.y += v.y; ae.z += v.z; ae.w += v.w;
        }
#pragma unroll
        for (int m = 8; m < 64; m <<= 1) {
            h0 += __shfl_xor(h0, m); h1 += __shfl_xor(h1, m);
            h2 += __shfl_xor(h2, m); h3 += __shfl_xor(h3, m);
            ae.x += __shfl_xor(ae.x, m); ae.y += __shfl_xor(ae.y, m);
            ae.z += __shfl_xor(ae.z, m); ae.w += __shfl_xor(ae.w, m);
        }
        if (lane < 8) {
            float* pe = eagg + (size_t)n * 32 + c * 4;
            float* ps = sea  + (size_t)n * 32 + c * 4;
            bool interior = (s0 >= P) && (e0 <= P + BP);
            if (interior) {
                float4 vh = {h0,h1,h2,h3};
                *reinterpret_cast<float4*>(pe) = vh;
                *reinterpret_cast<float4*>(ps) = ae;
            } else {
                atomicAdd(pe+0,h0); atomicAdd(pe+1,h1);
                atomicAdd(pe+2,h2); atomicAdd(pe+3,h3);
                atomicAdd(ps+0,ae.x); atomicAdd(ps+1,ae.y);
                atomicAdd(ps+2,ae.z); atomicAdd(ps+3,ae.w);
            }
        }
    }
}

// out[:,96:128] = dinv[i] * sum_{e:row=i} eagg[col[e]];  also copies eagg -> out[:,64:96]
__global__ __launch_bounds__(256) void k_mmagg(
    const int* __restrict__ colsort, const int* __restrict__ off,
    const float* __restrict__ eagg, float* __restrict__ out, int N)
{
    int wid  = (blockIdx.x * blockDim.x + threadIdx.x) >> 6;
    int lane = threadIdx.x & 63;
    if (wid >= N) return;
    int s = off[wid], e = off[wid + 1];
    int c   = lane & 7;
    int sub = lane >> 3;
    float4 acc = {0.f, 0.f, 0.f, 0.f};
    for (int t0 = s; t0 < e; t0 += 8) {
        int t = t0 + sub;
        if (t < e) {
            float4 v = reinterpret_cast<const float4*>(eagg + (size_t)colsort[t] * 32)[c];
            acc.x += v.x; acc.y += v.y; acc.z += v.z; acc.w += v.w;
        }
    }
#pragma unroll
    for (int m = 8; m < 64; m <<= 1) {
        acc.x += __shfl_xor(acc.x, m);
        acc.y += __shfl_xor(acc.y, m);
        acc.z += __shfl_xor(acc.z, m);
        acc.w += __shfl_xor(acc.w, m);
    }
    int dg = e - s;
    float dinv = dg > 0 ? rsqrtf((float)dg) : 0.f;
    if (lane < 8) {
        float4 o4 = {acc.x * dinv, acc.y * dinv, acc.z * dinv, acc.w * dinv};
        reinterpret_cast<float4*>(out + (size_t)wid * 224 + 96)[c] = o4;
        float4 eg = reinterpret_cast<const float4*>(eagg + (size_t)wid * 32)[c];
        reinterpret_cast<float4*>(out + (size_t)wid * 224 + 64)[c] = eg;
    }
}

// Fused ego+peer node GEMM. 64 nodes/block in LDS; wave q owns output quarter q.
#define TM 64
__global__ __launch_bounds__(256) void k_node(
    const float* __restrict__ x, const float* __restrict__ sea,
    const int* __restrict__ off,
    const float* __restrict__ W_ego, const float* __restrict__ b_ego,
    const float* __restrict__ W_peer, const float* __restrict__ b_peer,
    float* __restrict__ out, int N)
{
    __shared__ float a[TM][161];   // [x(128) | sea/deg(32) | sd(1)]
    const int tid = threadIdx.x;
    const int nb = blockIdx.x * TM;

    for (int f = tid; f < TM * 32; f += 256) {
        int n = f >> 5, c = f & 31;
        if (nb + n < N) {
            float4 v = reinterpret_cast<const float4*>(x + (size_t)(nb + n) * 128)[c];
            a[n][c*4+0] = v.x; a[n][c*4+1] = v.y; a[n][c*4+2] = v.z; a[n][c*4+3] = v.w;
        }
    }
    for (int f = tid; f < TM * 8; f += 256) {
        int n = f >> 3, c = f & 7;
        if (nb + n < N) {
            int dg = off[nb + n + 1] - off[nb + n];
            float r = dg > 0 ? 1.0f / (float)dg : 0.0f;
            float4 v = reinterpret_cast<const float4*>(sea + (size_t)(nb + n) * 32)[c];
            a[n][128 + c*4 + 0] = v.x * r;
            a[n][128 + c*4 + 1] = v.y * r;
            a[n][128 + c*4 + 2] = v.z * r;
            a[n][128 + c*4 + 3] = v.w * r;
            if (c == 0) a[n][160] = dg > 0 ? sqrtf((float)dg) : 0.0f;
        }
    }
    __syncthreads();

    const int lane = tid & 63;
    const int q = __builtin_amdgcn_readfirstlane(tid >> 6);
    const int node = nb + lane;

    float acc_e[16], acc_p[24];
#pragma unroll
    for (int j = 0; j < 16; ++j) acc_e[j] = 0.f;
#pragma unroll
    for (int j = 0; j < 24; ++j) acc_p[j] = 0.f;

    const float* We = W_ego  + q * 16 * 128;
    const float* Wp = W_peer + q * 24 * 160;

#pragma unroll 4
    for (int k = 0; k < 128; ++k) {
        float av = a[lane][k];
#pragma unroll
        for (int j = 0; j < 16; ++j) acc_e[j] = fmaf(We[j*128 + k], av, acc_e[j]);
#pragma unroll
        for (int j = 0; j < 24; ++j) acc_p[j] = fmaf(Wp[j*160 + k], av, acc_p[j]);
    }
#pragma unroll 4
    for (int k = 128; k < 160; ++k) {
        float av = a[lane][k];
#pragma unroll
        for (int j = 0; j < 24; ++j) acc_p[j] = fmaf(Wp[j*160 + k], av, acc_p[j]);
    }

    if (node >= N) return;
    float sd = a[lane][160];
    float* o = out + (size_t)node * 224;
#pragma unroll
    for (int j = 0; j < 16; ++j)
        o[q*16 + j] = fmaxf(acc_e[j] + b_ego[q*16 + j], 0.f);
#pragma unroll
    for (int j = 0; j < 24; ++j)
        o[128 + q*24 + j] = fmaxf(sd * (acc_p[j] + b_peer[q*24 + j]), 0.f);
}

extern "C" void kernel_launch(void* const* d_in, const int* in_sizes, int n_in,
                              void* d_out, int out_size, void* d_ws, size_t ws_size,
                              hipStream_t stream)
{
    const float* x      = (const float*)d_in[0];
    const float* ea     = (const float*)d_in[1];
    const float* W_peer = (const float*)d_in[2];
    const float* b_peer = (const float*)d_in[3];
    const float* W_ego  = (const float*)d_in[4];
    const float* b_ego  = (const float*)d_in[5];
    const float* W_edge = (const float*)d_in[6];
    const float* b_edge = (const float*)d_in[7];
    const int*   ei     = (const int*)d_in[8];

    const int N = in_sizes[0] / 128;
    const int E = in_sizes[8] / 2;
    const int* col = ei;        // edge_index[0]
    const int* row = ei + E;    // edge_index[1]

    // workspace: [deg N][eagg 32N][sea 32N][off N+1][cursor N][bsum 64][boff 64][eids E][colsort E]
    int*   deg_i   = (int*)d_ws;
    float* eagg    = (float*)(deg_i + N);        // 16B-aligned: N*4 % 16 == 0 (N=50000)
    float* sea     = eagg + (size_t)32 * N;
    int*   off     = (int*)(sea + (size_t)32 * N);
    int*   cursor  = off + (N + 1);
    int*   bsum    = cursor + N;
    int*   boff    = bsum + 64;
    int*   eids    = boff + 64;
    int*   colsort = eids + E;
    float* out     = (float*)d_out;

    // zero deg + eagg + sea in one shot (they're contiguous)
    hipMemsetAsync(d_ws, 0, (size_t)(65 * N) * sizeof(int), stream);

    const int TB = 256;
    const int NB = (N + 1023) / 1024;
    k_hist        <<<(E + TB - 1) / TB, TB, 0, stream>>>(row, deg_i, E);
    k_scan_partial<<<NB, TB, 0, stream>>>(deg_i, bsum, N);
    k_scan_mid    <<<1, 64, 0, stream>>>(bsum, boff, off, NB, N);
    k_scan_final  <<<NB, TB, 0, stream>>>(deg_i, boff, off, cursor, N);
    k_scatter     <<<(E + TB - 1) / TB, TB, 0, stream>>>(row, col, cursor, eids, colsort, E);

    k_fused<<<(E + BP - 1) / BP, BP, 0, stream>>>(ea, eids, off, W_edge, b_edge,
                                                  eagg, sea, N, E);

    const int agg_grid = (N + 3) / 4;   // 4 waves/block, 1 node/wave
    k_mmagg<<<agg_grid, TB, 0, stream>>>(colsort, off, eagg, out, N);
    k_node <<<(N + TM - 1) / TM, TB, 0, stream>>>(x, sea, off, W_ego, b_ego,
                                                  W_peer, b_peer, out, N);
}

// Round 5
// 246.714 us; speedup vs baseline: 17.5210x; 1.3593x over previous
//
#include <hip/hip_runtime.h>

// ---------------------------------------------------------------------------
// CSR build (1 int atomic/edge), fused edge GEMV + segmented aggregation,
// then MFMA (bf16) node-level GEMM:
//   out[:,  0: 64] = relu(x @ W_ego.T + b_ego)
//   out[:, 64: 96] = eagg[i]  = sum_{e:row=i} relu(ea[e] @ W_edge.T + b_edge)
//   out[:, 96:128] = dinv[i] * sum_{e:row=i} eagg[col[e]]
//   out[:,128:224] = relu( sd * (W_peer @ [x | sea/deg] + b_peer) )
// Node GEMM = [N x 160] @ [160 x 160] via mfma_f32_16x16x32_bf16.
// A/B fragment k-order cancels (same map both sides); C/D layout per guide:
// col = lane&15, row = (lane>>4)*4 + reg.
// ---------------------------------------------------------------------------

typedef float f32x4 __attribute__((ext_vector_type(4)));
typedef short bf16x8 __attribute__((ext_vector_type(8)));

__device__ __forceinline__ unsigned short f2bf(float f) {
    unsigned u = __float_as_uint(f);
    u += 0x7fffu + ((u >> 16) & 1u);      // RNE
    return (unsigned short)(u >> 16);
}
__device__ __forceinline__ bf16x8 pack8(float4 lo, float4 hi) {
    bf16x8 r;
    r[0]=(short)f2bf(lo.x); r[1]=(short)f2bf(lo.y); r[2]=(short)f2bf(lo.z); r[3]=(short)f2bf(lo.w);
    r[4]=(short)f2bf(hi.x); r[5]=(short)f2bf(hi.y); r[6]=(short)f2bf(hi.z); r[7]=(short)f2bf(hi.w);
    return r;
}

__global__ __launch_bounds__(256) void k_hist(const int* __restrict__ row,
                                              int* __restrict__ deg, int E) {
    int e = blockIdx.x * blockDim.x + threadIdx.x;
    if (e < E) atomicAdd(&deg[row[e]], 1);
}

__global__ __launch_bounds__(256) void k_scan_partial(const int* __restrict__ deg,
                                                      int* __restrict__ bsum, int N) {
    __shared__ int sh[256];
    int base = blockIdx.x * 1024 + threadIdx.x * 4;
    int s = 0;
#pragma unroll
    for (int q = 0; q < 4; ++q) { int i = base + q; if (i < N) s += deg[i]; }
    sh[threadIdx.x] = s;
    __syncthreads();
    for (int off = 128; off > 0; off >>= 1) {
        if (threadIdx.x < off) sh[threadIdx.x] += sh[threadIdx.x + off];
        __syncthreads();
    }
    if (threadIdx.x == 0) bsum[blockIdx.x] = sh[0];
}

__global__ void k_scan_mid(const int* __restrict__ bsum, int* __restrict__ boff,
                           int* __restrict__ off, int NB, int N) {
    if (threadIdx.x == 0 && blockIdx.x == 0) {
        int acc = 0;
        for (int b = 0; b < NB; ++b) { boff[b] = acc; acc += bsum[b]; }
        off[N] = acc;
    }
}

__global__ __launch_bounds__(256) void k_scan_final(const int* __restrict__ deg,
                                                    const int* __restrict__ boff,
                                                    int* __restrict__ off,
                                                    int* __restrict__ cursor, int N) {
    __shared__ int sh[256];
    int t = threadIdx.x;
    int base = blockIdx.x * 1024 + t * 4;
    int v[4];
#pragma unroll
    for (int q = 0; q < 4; ++q) v[q] = (base + q < N) ? deg[base + q] : 0;
    int ts = v[0] + v[1] + v[2] + v[3];
    sh[t] = ts;
    __syncthreads();
    int incl = ts;
    for (int d = 1; d < 256; d <<= 1) {
        int val = (t >= d) ? sh[t - d] : 0;
        __syncthreads();
        incl += val;
        sh[t] = incl;
        __syncthreads();
    }
    int running = boff[blockIdx.x] + incl - ts;
#pragma unroll
    for (int q = 0; q < 4; ++q) {
        int i = base + q;
        if (i < N) { off[i] = running; cursor[i] = running; running += v[q]; }
    }
}

__global__ __launch_bounds__(256) void k_scatter(const int* __restrict__ row,
                                                 const int* __restrict__ col,
                                                 int* __restrict__ cursor,
                                                 int* __restrict__ eids,
                                                 int* __restrict__ colsort, int E) {
    int e = blockIdx.x * blockDim.x + threadIdx.x;
    if (e >= E) return;
    int pos = atomicAdd(&cursor[row[e]], 1);
    eids[pos] = e;
    colsort[pos] = col[e];
}

// sd[i] = sqrt(deg), rdeg[i] = 1/deg (0 if deg==0)
__global__ __launch_bounds__(256) void k_prepsd(const int* __restrict__ off,
                                                float* __restrict__ sd,
                                                float* __restrict__ rdeg, int N) {
    int i = blockIdx.x * blockDim.x + threadIdx.x;
    if (i >= N) return;
    int dg = off[i + 1] - off[i];
    sd[i]   = dg > 0 ? sqrtf((float)dg) : 0.f;
    rdeg[i] = dg > 0 ? 1.f / (float)dg : 0.f;
}

// Bt[n][k] (bf16, 160x160): n<64 -> W_ego[n][k] (0 for k>=128); n>=64 -> W_peer[n-64][k]
__global__ __launch_bounds__(256) void k_prepB(const float* __restrict__ W_ego,
                                               const float* __restrict__ W_peer,
                                               unsigned short* __restrict__ Bt) {
    int idx = blockIdx.x * blockDim.x + threadIdx.x;
    if (idx >= 160 * 160) return;
    int n = idx / 160, k = idx % 160;
    float v;
    if (n < 64) v = (k < 128) ? W_ego[n * 128 + k] : 0.f;
    else        v = W_peer[(n - 64) * 160 + k];
    Bt[idx] = f2bf(v);
}

__device__ __forceinline__ int find_node(const int* __restrict__ off, int N, int p) {
    int lo = 0, hi = N;
    while (hi - lo > 1) { int mid = (lo + hi) >> 1; if (off[mid] <= p) lo = mid; else hi = mid; }
    return lo;
}

// Fused: per-edge GEMV (scalar weights) -> LDS -> segmented sum.
#define BP 128
__global__ __launch_bounds__(BP) void k_fused(
    const float* __restrict__ ea, const int* __restrict__ eids,
    const int* __restrict__ off,
    const float* __restrict__ W_edge, const float* __restrict__ b_edge,
    float* __restrict__ eagg, float* __restrict__ sea, int N, int E)
{
    __shared__ float hs[BP][33];
    __shared__ int eid_s[BP];
    const int tid = threadIdx.x;
    const int P = blockIdx.x * BP;
    const int p = P + tid;

    if (p < E) {
        int e = eids[p];
        eid_s[tid] = e;
        float a[32];
        const float4* r4 = reinterpret_cast<const float4*>(ea + (size_t)e * 32);
#pragma unroll
        for (int q = 0; q < 8; ++q) {
            float4 v = r4[q];
            a[4*q+0]=v.x; a[4*q+1]=v.y; a[4*q+2]=v.z; a[4*q+3]=v.w;
        }
#pragma unroll
        for (int j = 0; j < 32; ++j) {
            float h = b_edge[j];
#pragma unroll
            for (int k = 0; k < 32; ++k)
                h = fmaf(W_edge[j*32+k], a[k], h);
            hs[tid][j] = fmaxf(h, 0.f);
        }
    } else {
        eid_s[tid] = 0;
    }
    __syncthreads();

    const int pend = min(P + BP - 1, E - 1);
    const int node_lo = find_node(off, N, P);
    const int node_hi = find_node(off, N, pend);
    const int wv = tid >> 6, lane = tid & 63;
    const int c = lane & 7, sub = lane >> 3;

    for (int n = node_lo + wv; n <= node_hi; n += 2) {
        int s0 = off[n], e0 = off[n+1];
        int s = max(s0, P) - P, e = min(e0, P + BP) - P;
        float h0=0.f,h1=0.f,h2=0.f,h3=0.f;
        float4 ae = {0.f,0.f,0.f,0.f};
        for (int t = s + sub; t < e; t += 8) {
            h0 += hs[t][c*4+0];
            h1 += hs[t][c*4+1];
            h2 += hs[t][c*4+2];
            h3 += hs[t][c*4+3];
            float4 v = reinterpret_cast<const float4*>(ea + (size_t)eid_s[t] * 32)[c];
            ae.x += v.x; ae.y += v.y; ae.z += v.z; ae.w += v.w;
        }
#pragma unroll
        for (int m = 8; m < 64; m <<= 1) {
            h0 += __shfl_xor(h0, m); h1 += __shfl_xor(h1, m);
            h2 += __shfl_xor(h2, m); h3 += __shfl_xor(h3, m);
            ae.x += __shfl_xor(ae.x, m); ae.y += __shfl_xor(ae.y, m);
            ae.z += __shfl_xor(ae.z, m); ae.w += __shfl_xor(ae.w, m);
        }
        if (lane < 8) {
            float* pe = eagg + (size_t)n * 32 + c * 4;
            float* ps = sea  + (size_t)n * 32 + c * 4;
            bool interior = (s0 >= P) && (e0 <= P + BP);
            if (interior) {
                float4 vh = {h0,h1,h2,h3};
                *reinterpret_cast<float4*>(pe) = vh;
                *reinterpret_cast<float4*>(ps) = ae;
            } else {
                atomicAdd(pe+0,h0); atomicAdd(pe+1,h1);
                atomicAdd(pe+2,h2); atomicAdd(pe+3,h3);
                atomicAdd(ps+0,ae.x); atomicAdd(ps+1,ae.y);
                atomicAdd(ps+2,ae.z); atomicAdd(ps+3,ae.w);
            }
        }
    }
}

// out[:,96:128] = dinv * gather-sum(eagg[col]);  copies eagg -> out[:,64:96]
__global__ __launch_bounds__(256) void k_mmagg(
    const int* __restrict__ colsort, const int* __restrict__ off,
    const float* __restrict__ eagg, float* __restrict__ out, int N)
{
    int wid  = (blockIdx.x * blockDim.x + threadIdx.x) >> 6;
    int lane = threadIdx.x & 63;
    if (wid >= N) return;
    int s = off[wid], e = off[wid + 1];
    int c   = lane & 7;
    int sub = lane >> 3;
    float4 acc = {0.f, 0.f, 0.f, 0.f};
    for (int t0 = s; t0 < e; t0 += 8) {
        int t = t0 + sub;
        if (t < e) {
            float4 v = reinterpret_cast<const float4*>(eagg + (size_t)colsort[t] * 32)[c];
            acc.x += v.x; acc.y += v.y; acc.z += v.z; acc.w += v.w;
        }
    }
#pragma unroll
    for (int m = 8; m < 64; m <<= 1) {
        acc.x += __shfl_xor(acc.x, m);
        acc.y += __shfl_xor(acc.y, m);
        acc.z += __shfl_xor(acc.z, m);
        acc.w += __shfl_xor(acc.w, m);
    }
    int dg = e - s;
    float dinv = dg > 0 ? rsqrtf((float)dg) : 0.f;
    if (lane < 8) {
        float4 o4 = {acc.x * dinv, acc.y * dinv, acc.z * dinv, acc.w * dinv};
        reinterpret_cast<float4*>(out + (size_t)wid * 224 + 96)[c] = o4;
        float4 eg = reinterpret_cast<const float4*>(eagg + (size_t)wid * 32)[c];
        reinterpret_cast<float4*>(out + (size_t)wid * 224 + 64)[c] = eg;
    }
}

// MFMA node GEMM: block = 4 waves, wave = 16 nodes x 160 outputs, K = 160.
__global__ __launch_bounds__(256) void k_node3(
    const float* __restrict__ x, const float* __restrict__ sea,
    const float* __restrict__ sd, const float* __restrict__ rdeg,
    const unsigned short* __restrict__ Bt,
    const float* __restrict__ b_ego, const float* __restrict__ b_peer,
    float* __restrict__ out, int N)
{
    const int lane = threadIdx.x & 63;
    const int wv   = threadIdx.x >> 6;
    const int wm   = blockIdx.x * 64 + wv * 16;     // first node of wave tile
    const int n16  = lane & 15;
    const int h    = lane >> 4;

    const int m_l = min(wm + n16, N - 1);           // A-fragment row (clamped)

    f32x4 acc[10];
#pragma unroll
    for (int f = 0; f < 10; ++f) acc[f] = (f32x4){0.f,0.f,0.f,0.f};

#pragma unroll
    for (int kc = 0; kc < 5; ++kc) {
        // B fragments: Bt rows f*16+n16, k = kc*32 + h*4 (+16)
        bf16x8 bfr[10];
#pragma unroll
        for (int f = 0; f < 10; ++f) {
            const unsigned short* bp = Bt + (size_t)(f * 16 + n16) * 160 + kc * 32 + h * 4;
            ushort4 lo = *reinterpret_cast<const ushort4*>(bp);
            ushort4 hi = *reinterpret_cast<const ushort4*>(bp + 16);
            bf16x8 b;
            b[0]=(short)lo.x; b[1]=(short)lo.y; b[2]=(short)lo.z; b[3]=(short)lo.w;
            b[4]=(short)hi.x; b[5]=(short)hi.y; b[6]=(short)hi.z; b[7]=(short)hi.w;
            bfr[f] = b;
        }
        // A fragment: row m_l, k = kc*32 + h*4 (+16); kc==4 -> sea/deg
        float4 lo, hi;
        if (kc < 4) {
            const float* ap = x + (size_t)m_l * 128 + kc * 32 + h * 4;
            lo = *reinterpret_cast<const float4*>(ap);
            hi = *reinterpret_cast<const float4*>(ap + 16);
        } else {
            float r = rdeg[m_l];
            const float* ap = sea + (size_t)m_l * 32 + h * 4;
            lo = *reinterpret_cast<const float4*>(ap);
            hi = *reinterpret_cast<const float4*>(ap + 16);
            lo.x*=r; lo.y*=r; lo.z*=r; lo.w*=r;
            hi.x*=r; hi.y*=r; hi.z*=r; hi.w*=r;
        }
        bf16x8 a = pack8(lo, hi);
#pragma unroll
        for (int f = 0; f < 10; ++f)
            acc[f] = __builtin_amdgcn_mfma_f32_16x16x32_bf16(a, bfr[f], acc[f], 0, 0, 0);
    }

    // Epilogue: D[row][col]: col = n16 within frag, row = h*4 + r
    const int r4 = h * 4;
    float sdv[4];
#pragma unroll
    for (int r = 0; r < 4; ++r) {
        int node = wm + r4 + r;
        sdv[r] = (node < N) ? sd[node] : 0.f;
    }
#pragma unroll
    for (int f = 0; f < 10; ++f) {
        int c = f * 16 + n16;
        float be = (c < 64)  ? b_ego[c] : 0.f;
        float bp = (c >= 64) ? b_peer[c - 64] : 0.f;
#pragma unroll
        for (int r = 0; r < 4; ++r) {
            int node = wm + r4 + r;
            if (node >= N) continue;
            float v = acc[f][r];
            if (c < 64)
                out[(size_t)node * 224 + c] = fmaxf(v + be, 0.f);
            else
                out[(size_t)node * 224 + 64 + c] = fmaxf(sdv[r] * (v + bp), 0.f);
        }
    }
}

extern "C" void kernel_launch(void* const* d_in, const int* in_sizes, int n_in,
                              void* d_out, int out_size, void* d_ws, size_t ws_size,
                              hipStream_t stream)
{
    const float* x      = (const float*)d_in[0];
    const float* ea     = (const float*)d_in[1];
    const float* W_peer = (const float*)d_in[2];
    const float* b_peer = (const float*)d_in[3];
    const float* W_ego  = (const float*)d_in[4];
    const float* b_ego  = (const float*)d_in[5];
    const float* W_edge = (const float*)d_in[6];
    const float* b_edge = (const float*)d_in[7];
    const int*   ei     = (const int*)d_in[8];

    const int N = in_sizes[0] / 128;
    const int E = in_sizes[8] / 2;
    const int* col = ei;
    const int* row = ei + E;

    // ws: [deg N][eagg 32N][sea 32N][off N+1][cursor N][bsum 64][boff 64]
    //     [eids E][colsort E][sd N][rdeg N][Bt 160*160 u16]
    int*   deg_i   = (int*)d_ws;
    float* eagg    = (float*)(deg_i + N);
    float* sea     = eagg + (size_t)32 * N;
    int*   off     = (int*)(sea + (size_t)32 * N);
    int*   cursor  = off + (N + 1);
    int*   bsum    = cursor + N;
    int*   boff    = bsum + 64;
    int*   eids    = boff + 64;
    int*   colsort = eids + E;
    float* sd      = (float*)(colsort + E);
    float* rdeg    = sd + N;
    unsigned short* Bt = (unsigned short*)(rdeg + N);
    float* out     = (float*)d_out;

    hipMemsetAsync(d_ws, 0, (size_t)(65 * N) * sizeof(int), stream);

    const int TB = 256;
    const int NB = (N + 1023) / 1024;
    k_hist        <<<(E + TB - 1) / TB, TB, 0, stream>>>(row, deg_i, E);
    k_prepB       <<<(160*160 + TB - 1) / TB, TB, 0, stream>>>(W_ego, W_peer, Bt);
    k_scan_partial<<<NB, TB, 0, stream>>>(deg_i, bsum, N);
    k_scan_mid    <<<1, 64, 0, stream>>>(bsum, boff, off, NB, N);
    k_scan_final  <<<NB, TB, 0, stream>>>(deg_i, boff, off, cursor, N);
    k_prepsd      <<<(N + TB - 1) / TB, TB, 0, stream>>>(off, sd, rdeg, N);
    k_scatter     <<<(E + TB - 1) / TB, TB, 0, stream>>>(row, col, cursor, eids, colsort, E);

    k_fused<<<(E + BP - 1) / BP, BP, 0, stream>>>(ea, eids, off, W_edge, b_edge,
                                                  eagg, sea, N, E);

    const int agg_grid = (N + 3) / 4;
    k_mmagg<<<agg_grid, TB, 0, stream>>>(colsort, off, eagg, out, N);
    k_node3<<<(N + 63) / 64, TB, 0, stream>>>(x, sea, sd, rdeg, Bt,
                                              b_ego, b_peer, out, N);
}

// Round 6
// 232.623 us; speedup vs baseline: 18.5823x; 1.0606x over previous
//
#include <hip/hip_runtime.h>

// ---------------------------------------------------------------------------
// CSR build (1 int atomic/edge); fused MFMA edge-GEMV + segmented aggregation
// (raw ea staged in LDS, no global re-gather); MFMA bf16 node GEMM.
//   out[:,  0: 64] = relu(x @ W_ego.T + b_ego)
//   out[:, 64: 96] = eagg[i]  = sum_{e:row=i} relu(ea[e] @ W_edge.T + b_edge)
//   out[:, 96:128] = dinv[i] * sum_{e:row=i} eagg[col[e]]
//   out[:,128:224] = relu( sd * (W_peer @ [x | sea/deg] + b_peer) )
// MFMA fragment maps: A/B k-order cancels (same map both sides); C/D layout
// (HW-verified): col = lane&15, row = (lane>>4)*4 + reg.
// ---------------------------------------------------------------------------

typedef float f32x4 __attribute__((ext_vector_type(4)));
typedef short bf16x8 __attribute__((ext_vector_type(8)));

__device__ __forceinline__ unsigned short f2bf(float f) {
    unsigned u = __float_as_uint(f);
    u += 0x7fffu + ((u >> 16) & 1u);      // RNE
    return (unsigned short)(u >> 16);
}
__device__ __forceinline__ bf16x8 pack8(float4 lo, float4 hi) {
    bf16x8 r;
    r[0]=(short)f2bf(lo.x); r[1]=(short)f2bf(lo.y); r[2]=(short)f2bf(lo.z); r[3]=(short)f2bf(lo.w);
    r[4]=(short)f2bf(hi.x); r[5]=(short)f2bf(hi.y); r[6]=(short)f2bf(hi.z); r[7]=(short)f2bf(hi.w);
    return r;
}
__device__ __forceinline__ bf16x8 ld_bfrag(const unsigned short* bp) {
    ushort4 lo = *reinterpret_cast<const ushort4*>(bp);
    ushort4 hi = *reinterpret_cast<const ushort4*>(bp + 16);
    bf16x8 b;
    b[0]=(short)lo.x; b[1]=(short)lo.y; b[2]=(short)lo.z; b[3]=(short)lo.w;
    b[4]=(short)hi.x; b[5]=(short)hi.y; b[6]=(short)hi.z; b[7]=(short)hi.w;
    return b;
}

__global__ __launch_bounds__(256) void k_hist(const int* __restrict__ row,
                                              int* __restrict__ deg, int E) {
    int e = blockIdx.x * blockDim.x + threadIdx.x;
    if (e < E) atomicAdd(&deg[row[e]], 1);
}

__global__ __launch_bounds__(256) void k_scan_partial(const int* __restrict__ deg,
                                                      int* __restrict__ bsum, int N) {
    __shared__ int sh[256];
    int base = blockIdx.x * 1024 + threadIdx.x * 4;
    int s = 0;
#pragma unroll
    for (int q = 0; q < 4; ++q) { int i = base + q; if (i < N) s += deg[i]; }
    sh[threadIdx.x] = s;
    __syncthreads();
    for (int off = 128; off > 0; off >>= 1) {
        if (threadIdx.x < off) sh[threadIdx.x] += sh[threadIdx.x + off];
        __syncthreads();
    }
    if (threadIdx.x == 0) bsum[blockIdx.x] = sh[0];
}

__global__ void k_scan_mid(const int* __restrict__ bsum, int* __restrict__ boff,
                           int* __restrict__ off, int NB, int N) {
    if (threadIdx.x == 0 && blockIdx.x == 0) {
        int acc = 0;
        for (int b = 0; b < NB; ++b) { boff[b] = acc; acc += bsum[b]; }
        off[N] = acc;
    }
}

__global__ __launch_bounds__(256) void k_scan_final(const int* __restrict__ deg,
                                                    const int* __restrict__ boff,
                                                    int* __restrict__ off,
                                                    int* __restrict__ cursor, int N) {
    __shared__ int sh[256];
    int t = threadIdx.x;
    int base = blockIdx.x * 1024 + t * 4;
    int v[4];
#pragma unroll
    for (int q = 0; q < 4; ++q) v[q] = (base + q < N) ? deg[base + q] : 0;
    int ts = v[0] + v[1] + v[2] + v[3];
    sh[t] = ts;
    __syncthreads();
    int incl = ts;
    for (int d = 1; d < 256; d <<= 1) {
        int val = (t >= d) ? sh[t - d] : 0;
        __syncthreads();
        incl += val;
        sh[t] = incl;
        __syncthreads();
    }
    int running = boff[blockIdx.x] + incl - ts;
#pragma unroll
    for (int q = 0; q < 4; ++q) {
        int i = base + q;
        if (i < N) { off[i] = running; cursor[i] = running; running += v[q]; }
    }
}

__global__ __launch_bounds__(256) void k_scatter(const int* __restrict__ row,
                                                 const int* __restrict__ col,
                                                 int* __restrict__ cursor,
                                                 int* __restrict__ eids,
                                                 int* __restrict__ colsort, int E) {
    int e = blockIdx.x * blockDim.x + threadIdx.x;
    if (e >= E) return;
    int pos = atomicAdd(&cursor[row[e]], 1);
    eids[pos] = e;
    colsort[pos] = col[e];
}

__global__ __launch_bounds__(256) void k_prepsd(const int* __restrict__ off,
                                                float* __restrict__ sd,
                                                float* __restrict__ rdeg, int N) {
    int i = blockIdx.x * blockDim.x + threadIdx.x;
    if (i >= N) return;
    int dg = off[i + 1] - off[i];
    sd[i]   = dg > 0 ? sqrtf((float)dg) : 0.f;
    rdeg[i] = dg > 0 ? 1.f / (float)dg : 0.f;
}

// Bt[n][k] (bf16, 160x160) for node GEMM
__global__ __launch_bounds__(256) void k_prepB(const float* __restrict__ W_ego,
                                               const float* __restrict__ W_peer,
                                               unsigned short* __restrict__ Bt) {
    int idx = blockIdx.x * blockDim.x + threadIdx.x;
    if (idx >= 160 * 160) return;
    int n = idx / 160, k = idx % 160;
    float v;
    if (n < 64) v = (k < 128) ? W_ego[n * 128 + k] : 0.f;
    else        v = W_peer[(n - 64) * 160 + k];
    Bt[idx] = f2bf(v);
}

// Bte[j][k] (bf16, 32x32) for edge GEMV
__global__ __launch_bounds__(256) void k_prepBe(const float* __restrict__ W_edge,
                                                unsigned short* __restrict__ Bte) {
    int idx = blockIdx.x * blockDim.x + threadIdx.x;
    if (idx < 32 * 32) Bte[idx] = f2bf(W_edge[idx]);
}

__device__ __forceinline__ int find_node(const int* __restrict__ off, int N, int p) {
    int lo = 0, hi = N;
    while (hi - lo > 1) { int mid = (lo + hi) >> 1; if (off[mid] <= p) lo = mid; else hi = mid; }
    return lo;
}

// Fused: MFMA edge GEMV -> LDS (h_e and raw ea) -> segmented sum from LDS.
// 512 threads = 8 waves; 16 edges/wave; BP=128 CSR positions/block.
#define BP 128
__global__ __launch_bounds__(512) void k_fused(
    const float* __restrict__ ea, const int* __restrict__ eids,
    const int* __restrict__ off, const unsigned short* __restrict__ Bte,
    const float* __restrict__ b_edge,
    float* __restrict__ eagg, float* __restrict__ sea, int N, int E)
{
    __shared__ float hs [BP][36];   // relu(h_e) per block-local CSR position
    __shared__ float asr[BP][36];   // raw ea per block-local CSR position
    const int tid  = threadIdx.x;
    const int w    = tid >> 6;
    const int lane = tid & 63;
    const int n16  = lane & 15;
    const int h    = lane >> 4;
    const int P    = blockIdx.x * BP;

    // ---- phase 1: gather ea rows + MFMA GEMV ----
    {
        const int tA = w * 16 + n16;                 // block-local CSR pos
        const int p  = min(P + tA, E - 1);
        const int e  = eids[p];
        const float* ap = ea + (size_t)e * 32 + h * 4;
        float4 lo = *reinterpret_cast<const float4*>(ap);
        float4 hi = *reinterpret_cast<const float4*>(ap + 16);
        *reinterpret_cast<float4*>(&asr[tA][h * 4])      = lo;
        *reinterpret_cast<float4*>(&asr[tA][16 + h * 4]) = hi;
        bf16x8 afr = pack8(lo, hi);

        bf16x8 b0 = ld_bfrag(Bte + (size_t)n16 * 32 + h * 4);
        bf16x8 b1 = ld_bfrag(Bte + (size_t)(16 + n16) * 32 + h * 4);
        f32x4 d0 = {0.f,0.f,0.f,0.f}, d1 = {0.f,0.f,0.f,0.f};
        d0 = __builtin_amdgcn_mfma_f32_16x16x32_bf16(afr, b0, d0, 0, 0, 0);
        d1 = __builtin_amdgcn_mfma_f32_16x16x32_bf16(afr, b1, d1, 0, 0, 0);

        const int tr = w * 16 + h * 4;               // D row base = edge
        float be0 = b_edge[n16], be1 = b_edge[16 + n16];
#pragma unroll
        for (int r = 0; r < 4; ++r) {
            hs[tr + r][n16]      = fmaxf(d0[r] + be0, 0.f);
            hs[tr + r][16 + n16] = fmaxf(d1[r] + be1, 0.f);
        }
    }
    __syncthreads();

    // ---- phase 2: segmented sums from LDS ----
    const int pend = min(P + BP - 1, E - 1);
    const int node_lo = find_node(off, N, P);
    const int node_hi = find_node(off, N, pend);
    const int c = lane & 7, sub = lane >> 3;

    for (int n = node_lo + w; n <= node_hi; n += 8) {
        int s0 = off[n], e0 = off[n + 1];
        int s = max(s0, P) - P, eEnd = min(e0, P + BP) - P;
        float4 hv = {0.f,0.f,0.f,0.f}, av = {0.f,0.f,0.f,0.f};
        for (int t = s + sub; t < eEnd; t += 8) {
            float4 x1 = *reinterpret_cast<const float4*>(&hs [t][c * 4]);
            float4 x2 = *reinterpret_cast<const float4*>(&asr[t][c * 4]);
            hv.x += x1.x; hv.y += x1.y; hv.z += x1.z; hv.w += x1.w;
            av.x += x2.x; av.y += x2.y; av.z += x2.z; av.w += x2.w;
        }
#pragma unroll
        for (int m = 8; m < 64; m <<= 1) {
            hv.x += __shfl_xor(hv.x, m); hv.y += __shfl_xor(hv.y, m);
            hv.z += __shfl_xor(hv.z, m); hv.w += __shfl_xor(hv.w, m);
            av.x += __shfl_xor(av.x, m); av.y += __shfl_xor(av.y, m);
            av.z += __shfl_xor(av.z, m); av.w += __shfl_xor(av.w, m);
        }
        if (lane < 8) {
            float* pe = eagg + (size_t)n * 32 + c * 4;
            float* ps = sea  + (size_t)n * 32 + c * 4;
            bool interior = (s0 >= P) && (e0 <= P + BP);
            if (interior) {
                *reinterpret_cast<float4*>(pe) = hv;
                *reinterpret_cast<float4*>(ps) = av;
            } else {
                atomicAdd(pe+0,hv.x); atomicAdd(pe+1,hv.y);
                atomicAdd(pe+2,hv.z); atomicAdd(pe+3,hv.w);
                atomicAdd(ps+0,av.x); atomicAdd(ps+1,av.y);
                atomicAdd(ps+2,av.z); atomicAdd(ps+3,av.w);
            }
        }
    }
}

// out[:,96:128] = dinv * gather-sum(eagg[col]);  copies eagg -> out[:,64:96]
__global__ __launch_bounds__(256) void k_mmagg(
    const int* __restrict__ colsort, const int* __restrict__ off,
    const float* __restrict__ eagg, float* __restrict__ out, int N)
{
    int wid  = (blockIdx.x * blockDim.x + threadIdx.x) >> 6;
    int lane = threadIdx.x & 63;
    if (wid >= N) return;
    int s = off[wid], e = off[wid + 1];
    int c   = lane & 7;
    int sub = lane >> 3;
    float4 acc = {0.f, 0.f, 0.f, 0.f};
    for (int t0 = s; t0 < e; t0 += 8) {
        int t = t0 + sub;
        if (t < e) {
            float4 v = reinterpret_cast<const float4*>(eagg + (size_t)colsort[t] * 32)[c];
            acc.x += v.x; acc.y += v.y; acc.z += v.z; acc.w += v.w;
        }
    }
#pragma unroll
    for (int m = 8; m < 64; m <<= 1) {
        acc.x += __shfl_xor(acc.x, m);
        acc.y += __shfl_xor(acc.y, m);
        acc.z += __shfl_xor(acc.z, m);
        acc.w += __shfl_xor(acc.w, m);
    }
    int dg = e - s;
    float dinv = dg > 0 ? rsqrtf((float)dg) : 0.f;
    if (lane < 8) {
        float4 o4 = {acc.x * dinv, acc.y * dinv, acc.z * dinv, acc.w * dinv};
        reinterpret_cast<float4*>(out + (size_t)wid * 224 + 96)[c] = o4;
        float4 eg = reinterpret_cast<const float4*>(eagg + (size_t)wid * 32)[c];
        reinterpret_cast<float4*>(out + (size_t)wid * 224 + 64)[c] = eg;
    }
}

// MFMA node GEMM: block = 4 waves, wave = 16 nodes x 160 outputs, K = 160.
__global__ __launch_bounds__(256) void k_node3(
    const float* __restrict__ x, const float* __restrict__ sea,
    const float* __restrict__ sd, const float* __restrict__ rdeg,
    const unsigned short* __restrict__ Bt,
    const float* __restrict__ b_ego, const float* __restrict__ b_peer,
    float* __restrict__ out, int N)
{
    const int lane = threadIdx.x & 63;
    const int wv   = threadIdx.x >> 6;
    const int wm   = blockIdx.x * 64 + wv * 16;
    const int n16  = lane & 15;
    const int h    = lane >> 4;

    const int m_l = min(wm + n16, N - 1);

    f32x4 acc[10];
#pragma unroll
    for (int f = 0; f < 10; ++f) acc[f] = (f32x4){0.f,0.f,0.f,0.f};

#pragma unroll
    for (int kc = 0; kc < 5; ++kc) {
        bf16x8 bfr[10];
#pragma unroll
        for (int f = 0; f < 10; ++f)
            bfr[f] = ld_bfrag(Bt + (size_t)(f * 16 + n16) * 160 + kc * 32 + h * 4);
        float4 lo, hi;
        if (kc < 4) {
            const float* ap = x + (size_t)m_l * 128 + kc * 32 + h * 4;
            lo = *reinterpret_cast<const float4*>(ap);
            hi = *reinterpret_cast<const float4*>(ap + 16);
        } else {
            float r = rdeg[m_l];
            const float* ap = sea + (size_t)m_l * 32 + h * 4;
            lo = *reinterpret_cast<const float4*>(ap);
            hi = *reinterpret_cast<const float4*>(ap + 16);
            lo.x*=r; lo.y*=r; lo.z*=r; lo.w*=r;
            hi.x*=r; hi.y*=r; hi.z*=r; hi.w*=r;
        }
        bf16x8 a = pack8(lo, hi);
#pragma unroll
        for (int f = 0; f < 10; ++f)
            acc[f] = __builtin_amdgcn_mfma_f32_16x16x32_bf16(a, bfr[f], acc[f], 0, 0, 0);
    }

    const int r4 = h * 4;
    float sdv[4];
#pragma unroll
    for (int r = 0; r < 4; ++r) {
        int node = wm + r4 + r;
        sdv[r] = (node < N) ? sd[node] : 0.f;
    }
#pragma unroll
    for (int f = 0; f < 10; ++f) {
        int c = f * 16 + n16;
        float be = (c < 64)  ? b_ego[c] : 0.f;
        float bp = (c >= 64) ? b_peer[c - 64] : 0.f;
#pragma unroll
        for (int r = 0; r < 4; ++r) {
            int node = wm + r4 + r;
            if (node >= N) continue;
            float v = acc[f][r];
            if (c < 64)
                out[(size_t)node * 224 + c] = fmaxf(v + be, 0.f);
            else
                out[(size_t)node * 224 + 64 + c] = fmaxf(sdv[r] * (v + bp), 0.f);
        }
    }
}

extern "C" void kernel_launch(void* const* d_in, const int* in_sizes, int n_in,
                              void* d_out, int out_size, void* d_ws, size_t ws_size,
                              hipStream_t stream)
{
    const float* x      = (const float*)d_in[0];
    const float* ea     = (const float*)d_in[1];
    const float* W_peer = (const float*)d_in[2];
    const float* b_peer = (const float*)d_in[3];
    const float* W_ego  = (const float*)d_in[4];
    const float* b_ego  = (const float*)d_in[5];
    const float* W_edge = (const float*)d_in[6];
    const float* b_edge = (const float*)d_in[7];
    const int*   ei     = (const int*)d_in[8];

    const int N = in_sizes[0] / 128;
    const int E = in_sizes[8] / 2;
    const int* col = ei;
    const int* row = ei + E;

    int*   deg_i   = (int*)d_ws;
    float* eagg    = (float*)(deg_i + N);
    float* sea     = eagg + (size_t)32 * N;
    int*   off     = (int*)(sea + (size_t)32 * N);
    int*   cursor  = off + (N + 1);
    int*   bsum    = cursor + N;
    int*   boff    = bsum + 64;
    int*   eids    = boff + 64;
    int*   colsort = eids + E;
    float* sd      = (float*)(colsort + E);
    float* rdeg    = sd + N;
    unsigned short* Bt  = (unsigned short*)(rdeg + N);       // 160*160
    unsigned short* Bte = Bt + 160 * 160;                    // 32*32
    float* out     = (float*)d_out;

    hipMemsetAsync(d_ws, 0, (size_t)(65 * N) * sizeof(int), stream);

    const int TB = 256;
    const int NB = (N + 1023) / 1024;
    k_hist        <<<(E + TB - 1) / TB, TB, 0, stream>>>(row, deg_i, E);
    k_prepB       <<<(160*160 + TB - 1) / TB, TB, 0, stream>>>(W_ego, W_peer, Bt);
    k_prepBe      <<<(32*32 + TB - 1) / TB, TB, 0, stream>>>(W_edge, Bte);
    k_scan_partial<<<NB, TB, 0, stream>>>(deg_i, bsum, N);
    k_scan_mid    <<<1, 64, 0, stream>>>(bsum, boff, off, NB, N);
    k_scan_final  <<<NB, TB, 0, stream>>>(deg_i, boff, off, cursor, N);
    k_prepsd      <<<(N + TB - 1) / TB, TB, 0, stream>>>(off, sd, rdeg, N);
    k_scatter     <<<(E + TB - 1) / TB, TB, 0, stream>>>(row, col, cursor, eids, colsort, E);

    k_fused<<<(E + BP - 1) / BP, 512, 0, stream>>>(ea, eids, off, Bte, b_edge,
                                                   eagg, sea, N, E);

    const int agg_grid = (N + 3) / 4;
    k_mmagg<<<agg_grid, TB, 0, stream>>>(colsort, off, eagg, out, N);
    k_node3<<<(N + 63) / 64, TB, 0, stream>>>(x, sea, sd, rdeg, Bt,
                                              b_ego, b_peer, out, N);
}

// Round 7
// 222.698 us; speedup vs baseline: 19.4105x; 1.0446x over previous
//
#include <hip/hip_runtime.h>

// ---------------------------------------------------------------------------
// CSR build (1 int atomic/edge); fused MFMA edge-GEMV + segmented aggregation
// (raw ea staged in LDS; per-block first-node precomputed -> no binary
// search); MFMA bf16 node GEMM.
//   out[:,  0: 64] = relu(x @ W_ego.T + b_ego)
//   out[:, 64: 96] = eagg[i]  = sum_{e:row=i} relu(ea[e] @ W_edge.T + b_edge)
//   out[:, 96:128] = dinv[i] * sum_{e:row=i} eagg[col[e]]
//   out[:,128:224] = relu( sd * (W_peer @ [x | sea/deg] + b_peer) )
// MFMA fragment maps: A/B k-order cancels (same map both sides); C/D layout
// (HW-verified): col = lane&15, row = (lane>>4)*4 + reg.
// ---------------------------------------------------------------------------

typedef float f32x4 __attribute__((ext_vector_type(4)));
typedef short bf16x8 __attribute__((ext_vector_type(8)));

#define BP 128   // CSR positions per k_fused block

__device__ __forceinline__ unsigned short f2bf(float f) {
    unsigned u = __float_as_uint(f);
    u += 0x7fffu + ((u >> 16) & 1u);      // RNE
    return (unsigned short)(u >> 16);
}
__device__ __forceinline__ bf16x8 pack8(float4 lo, float4 hi) {
    bf16x8 r;
    r[0]=(short)f2bf(lo.x); r[1]=(short)f2bf(lo.y); r[2]=(short)f2bf(lo.z); r[3]=(short)f2bf(lo.w);
    r[4]=(short)f2bf(hi.x); r[5]=(short)f2bf(hi.y); r[6]=(short)f2bf(hi.z); r[7]=(short)f2bf(hi.w);
    return r;
}
__device__ __forceinline__ bf16x8 ld_bfrag(const unsigned short* bp) {
    ushort4 lo = *reinterpret_cast<const ushort4*>(bp);
    ushort4 hi = *reinterpret_cast<const ushort4*>(bp + 16);
    bf16x8 b;
    b[0]=(short)lo.x; b[1]=(short)lo.y; b[2]=(short)lo.z; b[3]=(short)lo.w;
    b[4]=(short)hi.x; b[5]=(short)hi.y; b[6]=(short)hi.z; b[7]=(short)hi.w;
    return b;
}

__global__ __launch_bounds__(256) void k_hist(const int* __restrict__ row,
                                              int* __restrict__ deg, int E) {
    int e = blockIdx.x * blockDim.x + threadIdx.x;
    if (e < E) atomicAdd(&deg[row[e]], 1);
}

__global__ __launch_bounds__(256) void k_scan_partial(const int* __restrict__ deg,
                                                      int* __restrict__ bsum, int N) {
    __shared__ int sh[256];
    int base = blockIdx.x * 1024 + threadIdx.x * 4;
    int s = 0;
#pragma unroll
    for (int q = 0; q < 4; ++q) { int i = base + q; if (i < N) s += deg[i]; }
    sh[threadIdx.x] = s;
    __syncthreads();
    for (int off = 128; off > 0; off >>= 1) {
        if (threadIdx.x < off) sh[threadIdx.x] += sh[threadIdx.x + off];
        __syncthreads();
    }
    if (threadIdx.x == 0) bsum[blockIdx.x] = sh[0];
}

__global__ void k_scan_mid(const int* __restrict__ bsum, int* __restrict__ boff,
                           int* __restrict__ off, int NB, int N) {
    if (threadIdx.x == 0 && blockIdx.x == 0) {
        int acc = 0;
        for (int b = 0; b < NB; ++b) { boff[b] = acc; acc += bsum[b]; }
        off[N] = acc;
    }
}

__global__ __launch_bounds__(256) void k_scan_final(const int* __restrict__ deg,
                                                    const int* __restrict__ boff,
                                                    int* __restrict__ off,
                                                    int* __restrict__ cursor, int N) {
    __shared__ int sh[256];
    int t = threadIdx.x;
    int base = blockIdx.x * 1024 + t * 4;
    int v[4];
#pragma unroll
    for (int q = 0; q < 4; ++q) v[q] = (base + q < N) ? deg[base + q] : 0;
    int ts = v[0] + v[1] + v[2] + v[3];
    sh[t] = ts;
    __syncthreads();
    int incl = ts;
    for (int d = 1; d < 256; d <<= 1) {
        int val = (t >= d) ? sh[t - d] : 0;
        __syncthreads();
        incl += val;
        sh[t] = incl;
        __syncthreads();
    }
    int running = boff[blockIdx.x] + incl - ts;
#pragma unroll
    for (int q = 0; q < 4; ++q) {
        int i = base + q;
        if (i < N) { off[i] = running; cursor[i] = running; running += v[q]; }
    }
}

__global__ __launch_bounds__(256) void k_scatter(const int* __restrict__ row,
                                                 const int* __restrict__ col,
                                                 int* __restrict__ cursor,
                                                 int* __restrict__ eids,
                                                 int* __restrict__ colsort, int E) {
    int e = blockIdx.x * blockDim.x + threadIdx.x;
    if (e >= E) return;
    int pos = atomicAdd(&cursor[row[e]], 1);
    eids[pos] = e;
    colsort[pos] = col[e];
}

// sd/rdeg per node + nstart[b] = node containing CSR position b*BP
__global__ __launch_bounds__(256) void k_prepsd(const int* __restrict__ off,
                                                float* __restrict__ sd,
                                                float* __restrict__ rdeg,
                                                int* __restrict__ nstart, int N) {
    int i = blockIdx.x * blockDim.x + threadIdx.x;
    if (i >= N) return;
    int s = off[i], e = off[i + 1];
    int dg = e - s;
    sd[i]   = dg > 0 ? sqrtf((float)dg) : 0.f;
    rdeg[i] = dg > 0 ? 1.f / (float)dg : 0.f;
    for (int b = (s + BP - 1) / BP; b * BP < e; ++b) nstart[b] = i;
}

// Bt[n][k] (bf16,160x160) for node GEMM + Bte[j][k] (bf16,32x32) for edge GEMV
__global__ __launch_bounds__(256) void k_prepw(const float* __restrict__ W_ego,
                                               const float* __restrict__ W_peer,
                                               const float* __restrict__ W_edge,
                                               unsigned short* __restrict__ Bt,
                                               unsigned short* __restrict__ Bte) {
    int idx = blockIdx.x * blockDim.x + threadIdx.x;
    if (idx < 160 * 160) {
        int n = idx / 160, k = idx % 160;
        float v;
        if (n < 64) v = (k < 128) ? W_ego[n * 128 + k] : 0.f;
        else        v = W_peer[(n - 64) * 160 + k];
        Bt[idx] = f2bf(v);
    } else if (idx < 160 * 160 + 32 * 32) {
        int j = idx - 160 * 160;
        Bte[j] = f2bf(W_edge[j]);
    }
}

// Fused: MFMA edge GEMV -> LDS (h_e and raw ea) -> segmented sum from LDS.
// 512 threads = 8 waves; 16 edges/wave; BP=128 CSR positions/block.
__global__ __launch_bounds__(512) void k_fused(
    const float* __restrict__ ea, const int* __restrict__ eids,
    const int* __restrict__ off, const int* __restrict__ nstart,
    const unsigned short* __restrict__ Bte, const float* __restrict__ b_edge,
    float* __restrict__ eagg, float* __restrict__ sea, int N, int E)
{
    __shared__ float hs [BP][36];   // relu(h_e) per block-local CSR position
    __shared__ float asr[BP][36];   // raw ea per block-local CSR position
    const int tid  = threadIdx.x;
    const int w    = tid >> 6;
    const int lane = tid & 63;
    const int n16  = lane & 15;
    const int h    = lane >> 4;
    const int P    = blockIdx.x * BP;

    // ---- phase 1: gather ea rows + MFMA GEMV ----
    {
        const int tA = w * 16 + n16;                 // block-local CSR pos
        const int p  = min(P + tA, E - 1);
        const int e  = eids[p];
        const float* ap = ea + (size_t)e * 32 + h * 4;
        float4 lo = *reinterpret_cast<const float4*>(ap);
        float4 hi = *reinterpret_cast<const float4*>(ap + 16);
        *reinterpret_cast<float4*>(&asr[tA][h * 4])      = lo;
        *reinterpret_cast<float4*>(&asr[tA][16 + h * 4]) = hi;
        bf16x8 afr = pack8(lo, hi);

        bf16x8 b0 = ld_bfrag(Bte + (size_t)n16 * 32 + h * 4);
        bf16x8 b1 = ld_bfrag(Bte + (size_t)(16 + n16) * 32 + h * 4);
        f32x4 d0 = {0.f,0.f,0.f,0.f}, d1 = {0.f,0.f,0.f,0.f};
        d0 = __builtin_amdgcn_mfma_f32_16x16x32_bf16(afr, b0, d0, 0, 0, 0);
        d1 = __builtin_amdgcn_mfma_f32_16x16x32_bf16(afr, b1, d1, 0, 0, 0);

        const int tr = w * 16 + h * 4;               // D row base = edge
        float be0 = b_edge[n16], be1 = b_edge[16 + n16];
#pragma unroll
        for (int r = 0; r < 4; ++r) {
            hs[tr + r][n16]      = fmaxf(d0[r] + be0, 0.f);
            hs[tr + r][16 + n16] = fmaxf(d1[r] + be1, 0.f);
        }
    }
    __syncthreads();

    // ---- phase 2: segmented sums from LDS (no search: nstart precomputed) ----
    const int c = lane & 7, sub = lane >> 3;
    const int node0 = nstart[blockIdx.x];

    for (int n = node0 + w; n < N; n += 8) {
        int s0 = off[n];
        if (s0 >= P + BP) break;                     // off monotone -> done
        int e0 = off[n + 1];
        int s = max(s0, P) - P, eEnd = min(e0, P + BP) - P;
        float4 hv = {0.f,0.f,0.f,0.f}, av = {0.f,0.f,0.f,0.f};
        for (int t = s + sub; t < eEnd; t += 8) {
            float4 x1 = *reinterpret_cast<const float4*>(&hs [t][c * 4]);
            float4 x2 = *reinterpret_cast<const float4*>(&asr[t][c * 4]);
            hv.x += x1.x; hv.y += x1.y; hv.z += x1.z; hv.w += x1.w;
            av.x += x2.x; av.y += x2.y; av.z += x2.z; av.w += x2.w;
        }
#pragma unroll
        for (int m = 8; m < 64; m <<= 1) {
            hv.x += __shfl_xor(hv.x, m); hv.y += __shfl_xor(hv.y, m);
            hv.z += __shfl_xor(hv.z, m); hv.w += __shfl_xor(hv.w, m);
            av.x += __shfl_xor(av.x, m); av.y += __shfl_xor(av.y, m);
            av.z += __shfl_xor(av.z, m); av.w += __shfl_xor(av.w, m);
        }
        if (lane < 8) {
            float* pe = eagg + (size_t)n * 32 + c * 4;
            float* ps = sea  + (size_t)n * 32 + c * 4;
            bool interior = (s0 >= P) && (e0 <= P + BP);
            if (interior) {
                *reinterpret_cast<float4*>(pe) = hv;
                *reinterpret_cast<float4*>(ps) = av;
            } else {
                atomicAdd(pe+0,hv.x); atomicAdd(pe+1,hv.y);
                atomicAdd(pe+2,hv.z); atomicAdd(pe+3,hv.w);
                atomicAdd(ps+0,av.x); atomicAdd(ps+1,av.y);
                atomicAdd(ps+2,av.z); atomicAdd(ps+3,av.w);
            }
        }
    }
}

// out[:,96:128] = dinv * gather-sum(eagg[col]);  copies eagg -> out[:,64:96]
__global__ __launch_bounds__(256) void k_mmagg(
    const int* __restrict__ colsort, const int* __restrict__ off,
    const float* __restrict__ eagg, float* __restrict__ out, int N)
{
    int wid  = (blockIdx.x * blockDim.x + threadIdx.x) >> 6;
    int lane = threadIdx.x & 63;
    if (wid >= N) return;
    int s = off[wid], e = off[wid + 1];
    int c   = lane & 7;
    int sub = lane >> 3;
    float4 acc = {0.f, 0.f, 0.f, 0.f};
    for (int t0 = s; t0 < e; t0 += 8) {
        int t = t0 + sub;
        if (t < e) {
            float4 v = reinterpret_cast<const float4*>(eagg + (size_t)colsort[t] * 32)[c];
            acc.x += v.x; acc.y += v.y; acc.z += v.z; acc.w += v.w;
        }
    }
#pragma unroll
    for (int m = 8; m < 64; m <<= 1) {
        acc.x += __shfl_xor(acc.x, m);
        acc.y += __shfl_xor(acc.y, m);
        acc.z += __shfl_xor(acc.z, m);
        acc.w += __shfl_xor(acc.w, m);
    }
    int dg = e - s;
    float dinv = dg > 0 ? rsqrtf((float)dg) : 0.f;
    if (lane < 8) {
        float4 o4 = {acc.x * dinv, acc.y * dinv, acc.z * dinv, acc.w * dinv};
        reinterpret_cast<float4*>(out + (size_t)wid * 224 + 96)[c] = o4;
        float4 eg = reinterpret_cast<const float4*>(eagg + (size_t)wid * 32)[c];
        reinterpret_cast<float4*>(out + (size_t)wid * 224 + 64)[c] = eg;
    }
}

// MFMA node GEMM: block = 4 waves, wave = 16 nodes x 160 outputs, K = 160.
__global__ __launch_bounds__(256) void k_node3(
    const float* __restrict__ x, const float* __restrict__ sea,
    const float* __restrict__ sd, const float* __restrict__ rdeg,
    const unsigned short* __restrict__ Bt,
    const float* __restrict__ b_ego, const float* __restrict__ b_peer,
    float* __restrict__ out, int N)
{
    const int lane = threadIdx.x & 63;
    const int wv   = threadIdx.x >> 6;
    const int wm   = blockIdx.x * 64 + wv * 16;
    const int n16  = lane & 15;
    const int h    = lane >> 4;

    const int m_l = min(wm + n16, N - 1);

    f32x4 acc[10];
#pragma unroll
    for (int f = 0; f < 10; ++f) acc[f] = (f32x4){0.f,0.f,0.f,0.f};

#pragma unroll
    for (int kc = 0; kc < 5; ++kc) {
        bf16x8 bfr[10];
#pragma unroll
        for (int f = 0; f < 10; ++f)
            bfr[f] = ld_bfrag(Bt + (size_t)(f * 16 + n16) * 160 + kc * 32 + h * 4);
        float4 lo, hi;
        if (kc < 4) {
            const float* ap = x + (size_t)m_l * 128 + kc * 32 + h * 4;
            lo = *reinterpret_cast<const float4*>(ap);
            hi = *reinterpret_cast<const float4*>(ap + 16);
        } else {
            float r = rdeg[m_l];
            const float* ap = sea + (size_t)m_l * 32 + h * 4;
            lo = *reinterpret_cast<const float4*>(ap);
            hi = *reinterpret_cast<const float4*>(ap + 16);
            lo.x*=r; lo.y*=r; lo.z*=r; lo.w*=r;
            hi.x*=r; hi.y*=r; hi.z*=r; hi.w*=r;
        }
        bf16x8 a = pack8(lo, hi);
#pragma unroll
        for (int f = 0; f < 10; ++f)
            acc[f] = __builtin_amdgcn_mfma_f32_16x16x32_bf16(a, bfr[f], acc[f], 0, 0, 0);
    }

    const int r4 = h * 4;
    float sdv[4];
#pragma unroll
    for (int r = 0; r < 4; ++r) {
        int node = wm + r4 + r;
        sdv[r] = (node < N) ? sd[node] : 0.f;
    }
#pragma unroll
    for (int f = 0; f < 10; ++f) {
        int c = f * 16 + n16;
        float be = (c < 64)  ? b_ego[c] : 0.f;
        float bp = (c >= 64) ? b_peer[c - 64] : 0.f;
#pragma unroll
        for (int r = 0; r < 4; ++r) {
            int node = wm + r4 + r;
            if (node >= N) continue;
            float v = acc[f][r];
            if (c < 64)
                out[(size_t)node * 224 + c] = fmaxf(v + be, 0.f);
            else
                out[(size_t)node * 224 + 64 + c] = fmaxf(sdv[r] * (v + bp), 0.f);
        }
    }
}

extern "C" void kernel_launch(void* const* d_in, const int* in_sizes, int n_in,
                              void* d_out, int out_size, void* d_ws, size_t ws_size,
                              hipStream_t stream)
{
    const float* x      = (const float*)d_in[0];
    const float* ea     = (const float*)d_in[1];
    const float* W_peer = (const float*)d_in[2];
    const float* b_peer = (const float*)d_in[3];
    const float* W_ego  = (const float*)d_in[4];
    const float* b_ego  = (const float*)d_in[5];
    const float* W_edge = (const float*)d_in[6];
    const float* b_edge = (const float*)d_in[7];
    const int*   ei     = (const int*)d_in[8];

    const int N = in_sizes[0] / 128;
    const int E = in_sizes[8] / 2;
    const int* col = ei;
    const int* row = ei + E;
    const int nblocks = (E + BP - 1) / BP;

    int*   deg_i   = (int*)d_ws;
    float* eagg    = (float*)(deg_i + N);
    float* sea     = eagg + (size_t)32 * N;
    int*   off     = (int*)(sea + (size_t)32 * N);
    int*   cursor  = off + (N + 1);
    int*   bsum    = cursor + N;
    int*   boff    = bsum + 64;
    int*   eids    = boff + 64;
    int*   colsort = eids + E;
    float* sd      = (float*)(colsort + E);
    float* rdeg    = sd + N;
    int*   nstart  = (int*)(rdeg + N);                       // [nblocks]
    unsigned short* Bt  = (unsigned short*)(nstart + nblocks); // 160*160
    unsigned short* Bte = Bt + 160 * 160;                    // 32*32
    float* out     = (float*)d_out;

    hipMemsetAsync(d_ws, 0, (size_t)(65 * N) * sizeof(int), stream);

    const int TB = 256;
    const int NB = (N + 1023) / 1024;
    k_hist        <<<(E + TB - 1) / TB, TB, 0, stream>>>(row, deg_i, E);
    k_prepw       <<<(160*160 + 32*32 + TB - 1) / TB, TB, 0, stream>>>(W_ego, W_peer, W_edge, Bt, Bte);
    k_scan_partial<<<NB, TB, 0, stream>>>(deg_i, bsum, N);
    k_scan_mid    <<<1, 64, 0, stream>>>(bsum, boff, off, NB, N);
    k_scan_final  <<<NB, TB, 0, stream>>>(deg_i, boff, off, cursor, N);
    k_prepsd      <<<(N + TB - 1) / TB, TB, 0, stream>>>(off, sd, rdeg, nstart, N);
    k_scatter     <<<(E + TB - 1) / TB, TB, 0, stream>>>(row, col, cursor, eids, colsort, E);

    k_fused<<<nblocks, 512, 0, stream>>>(ea, eids, off, nstart, Bte, b_edge,
                                         eagg, sea, N, E);

    const int agg_grid = (N + 3) / 4;
    k_mmagg<<<agg_grid, TB, 0, stream>>>(colsort, off, eagg, out, N);
    k_node3<<<(N + 63) / 64, TB, 0, stream>>>(x, sea, sd, rdeg, Bt,
                                              b_ego, b_peer, out, N);
}

// Round 8
// 215.402 us; speedup vs baseline: 20.0679x; 1.0339x over previous
//
#include <hip/hip_runtime.h>

// ---------------------------------------------------------------------------
// CSR build (1 int atomic/edge); fused MFMA edge-GEMV + segmented aggregation
// (2 edges/thread for 2x memory-level parallelism, bf16 LDS tiles, per-block
// first-node precomputed); MFMA bf16 node GEMM.
//   out[:,  0: 64] = relu(x @ W_ego.T + b_ego)
//   out[:, 64: 96] = eagg[i]  = sum_{e:row=i} relu(ea[e] @ W_edge.T + b_edge)
//   out[:, 96:128] = dinv[i] * sum_{e:row=i} eagg[col[e]]
//   out[:,128:224] = relu( sd * (W_peer @ [x | sea/deg] + b_peer) )
// MFMA fragment maps: A/B k-order cancels (same map both sides); C/D layout
// (HW-verified): col = lane&15, row = (lane>>4)*4 + reg.
// ---------------------------------------------------------------------------

typedef float f32x4 __attribute__((ext_vector_type(4)));
typedef short bf16x8 __attribute__((ext_vector_type(8)));

#define BP 256   // CSR positions per k_fused block (512 threads, 2 edges/thread)

__device__ __forceinline__ unsigned short f2bf(float f) {
    unsigned u = __float_as_uint(f);
    u += 0x7fffu + ((u >> 16) & 1u);      // RNE
    return (unsigned short)(u >> 16);
}
__device__ __forceinline__ float bf2f(unsigned short u) {
    return __uint_as_float((unsigned)u << 16);
}
__device__ __forceinline__ ushort4 pk4(float4 v) {
    return (ushort4){f2bf(v.x), f2bf(v.y), f2bf(v.z), f2bf(v.w)};
}
__device__ __forceinline__ bf16x8 pack8(float4 lo, float4 hi) {
    bf16x8 r;
    r[0]=(short)f2bf(lo.x); r[1]=(short)f2bf(lo.y); r[2]=(short)f2bf(lo.z); r[3]=(short)f2bf(lo.w);
    r[4]=(short)f2bf(hi.x); r[5]=(short)f2bf(hi.y); r[6]=(short)f2bf(hi.z); r[7]=(short)f2bf(hi.w);
    return r;
}
__device__ __forceinline__ bf16x8 ld_bfrag(const unsigned short* bp) {
    ushort4 lo = *reinterpret_cast<const ushort4*>(bp);
    ushort4 hi = *reinterpret_cast<const ushort4*>(bp + 16);
    bf16x8 b;
    b[0]=(short)lo.x; b[1]=(short)lo.y; b[2]=(short)lo.z; b[3]=(short)lo.w;
    b[4]=(short)hi.x; b[5]=(short)hi.y; b[6]=(short)hi.z; b[7]=(short)hi.w;
    return b;
}

__global__ __launch_bounds__(256) void k_hist(const int* __restrict__ row,
                                              int* __restrict__ deg, int E) {
    int e = blockIdx.x * blockDim.x + threadIdx.x;
    if (e < E) atomicAdd(&deg[row[e]], 1);
}

__global__ __launch_bounds__(256) void k_scan_partial(const int* __restrict__ deg,
                                                      int* __restrict__ bsum, int N) {
    __shared__ int sh[256];
    int base = blockIdx.x * 1024 + threadIdx.x * 4;
    int s = 0;
#pragma unroll
    for (int q = 0; q < 4; ++q) { int i = base + q; if (i < N) s += deg[i]; }
    sh[threadIdx.x] = s;
    __syncthreads();
    for (int off = 128; off > 0; off >>= 1) {
        if (threadIdx.x < off) sh[threadIdx.x] += sh[threadIdx.x + off];
        __syncthreads();
    }
    if (threadIdx.x == 0) bsum[blockIdx.x] = sh[0];
}

__global__ void k_scan_mid(const int* __restrict__ bsum, int* __restrict__ boff,
                           int* __restrict__ off, int NB, int N) {
    if (threadIdx.x == 0 && blockIdx.x == 0) {
        int acc = 0;
        for (int b = 0; b < NB; ++b) { boff[b] = acc; acc += bsum[b]; }
        off[N] = acc;
    }
}

__global__ __launch_bounds__(256) void k_scan_final(const int* __restrict__ deg,
                                                    const int* __restrict__ boff,
                                                    int* __restrict__ off,
                                                    int* __restrict__ cursor, int N) {
    __shared__ int sh[256];
    int t = threadIdx.x;
    int base = blockIdx.x * 1024 + t * 4;
    int v[4];
#pragma unroll
    for (int q = 0; q < 4; ++q) v[q] = (base + q < N) ? deg[base + q] : 0;
    int ts = v[0] + v[1] + v[2] + v[3];
    sh[t] = ts;
    __syncthreads();
    int incl = ts;
    for (int d = 1; d < 256; d <<= 1) {
        int val = (t >= d) ? sh[t - d] : 0;
        __syncthreads();
        incl += val;
        sh[t] = incl;
        __syncthreads();
    }
    int running = boff[blockIdx.x] + incl - ts;
#pragma unroll
    for (int q = 0; q < 4; ++q) {
        int i = base + q;
        if (i < N) { off[i] = running; cursor[i] = running; running += v[q]; }
    }
}

__global__ __launch_bounds__(256) void k_scatter(const int* __restrict__ row,
                                                 const int* __restrict__ col,
                                                 int* __restrict__ cursor,
                                                 int* __restrict__ eids,
                                                 int* __restrict__ colsort, int E) {
    int e = blockIdx.x * blockDim.x + threadIdx.x;
    if (e >= E) return;
    int pos = atomicAdd(&cursor[row[e]], 1);
    eids[pos] = e;
    colsort[pos] = col[e];
}

// sd/rdeg per node + nstart[b] = node containing CSR position b*BP
__global__ __launch_bounds__(256) void k_prepsd(const int* __restrict__ off,
                                                float* __restrict__ sd,
                                                float* __restrict__ rdeg,
                                                int* __restrict__ nstart, int N) {
    int i = blockIdx.x * blockDim.x + threadIdx.x;
    if (i >= N) return;
    int s = off[i], e = off[i + 1];
    int dg = e - s;
    sd[i]   = dg > 0 ? sqrtf((float)dg) : 0.f;
    rdeg[i] = dg > 0 ? 1.f / (float)dg : 0.f;
    for (int b = (s + BP - 1) / BP; b * BP < e; ++b) nstart[b] = i;
}

// Bt[n][k] (bf16,160x160) for node GEMM + Bte[j][k] (bf16,32x32) for edge GEMV
__global__ __launch_bounds__(256) void k_prepw(const float* __restrict__ W_ego,
                                               const float* __restrict__ W_peer,
                                               const float* __restrict__ W_edge,
                                               unsigned short* __restrict__ Bt,
                                               unsigned short* __restrict__ Bte) {
    int idx = blockIdx.x * blockDim.x + threadIdx.x;
    if (idx < 160 * 160) {
        int n = idx / 160, k = idx % 160;
        float v;
        if (n < 64) v = (k < 128) ? W_ego[n * 128 + k] : 0.f;
        else        v = W_peer[(n - 64) * 160 + k];
        Bt[idx] = f2bf(v);
    } else if (idx < 160 * 160 + 32 * 32) {
        int j = idx - 160 * 160;
        Bte[j] = f2bf(W_edge[j]);
    }
}

// Fused: MFMA edge GEMV (2 edges/thread) -> bf16 LDS -> segmented sum.
// 512 threads = 8 waves; 32 edges/wave; BP=256 CSR positions/block.
__global__ __launch_bounds__(512) void k_fused(
    const float* __restrict__ ea, const int* __restrict__ eids,
    const int* __restrict__ off, const int* __restrict__ nstart,
    const unsigned short* __restrict__ Bte, const float* __restrict__ b_edge,
    float* __restrict__ eagg, float* __restrict__ sea, int N, int E)
{
    __shared__ unsigned short hs [BP][36];   // relu(h_e), bf16
    __shared__ unsigned short asr[BP][36];   // raw ea,    bf16
    const int tid  = threadIdx.x;
    const int w    = tid >> 6;
    const int lane = tid & 63;
    const int n16  = lane & 15;
    const int h    = lane >> 4;
    const int P    = blockIdx.x * BP;

    // ---- phase 1: gather 2 ea rows + 2 MFMA GEMV tiles per wave-pair ----
    {
        const int tA = w * 32 + n16;                 // block-local CSR pos (tile 0)
        const int p0 = min(P + tA,      E - 1);
        const int p1 = min(P + tA + 16, E - 1);
        const int e0i = eids[p0];
        const int e1i = eids[p1];
        const float* ap0 = ea + (size_t)e0i * 32 + h * 4;
        const float* ap1 = ea + (size_t)e1i * 32 + h * 4;
        float4 lo0 = *reinterpret_cast<const float4*>(ap0);
        float4 hi0 = *reinterpret_cast<const float4*>(ap0 + 16);
        float4 lo1 = *reinterpret_cast<const float4*>(ap1);
        float4 hi1 = *reinterpret_cast<const float4*>(ap1 + 16);

        *reinterpret_cast<ushort4*>(&asr[tA][h * 4])           = pk4(lo0);
        *reinterpret_cast<ushort4*>(&asr[tA][16 + h * 4])      = pk4(hi0);
        *reinterpret_cast<ushort4*>(&asr[tA + 16][h * 4])      = pk4(lo1);
        *reinterpret_cast<ushort4*>(&asr[tA + 16][16 + h * 4]) = pk4(hi1);

        bf16x8 a0 = pack8(lo0, hi0);
        bf16x8 a1 = pack8(lo1, hi1);
        bf16x8 b0 = ld_bfrag(Bte + (size_t)n16 * 32 + h * 4);
        bf16x8 b1 = ld_bfrag(Bte + (size_t)(16 + n16) * 32 + h * 4);
        f32x4 d00 = {0.f,0.f,0.f,0.f}, d01 = {0.f,0.f,0.f,0.f};
        f32x4 d10 = {0.f,0.f,0.f,0.f}, d11 = {0.f,0.f,0.f,0.f};
        d00 = __builtin_amdgcn_mfma_f32_16x16x32_bf16(a0, b0, d00, 0, 0, 0);
        d01 = __builtin_amdgcn_mfma_f32_16x16x32_bf16(a0, b1, d01, 0, 0, 0);
        d10 = __builtin_amdgcn_mfma_f32_16x16x32_bf16(a1, b0, d10, 0, 0, 0);
        d11 = __builtin_amdgcn_mfma_f32_16x16x32_bf16(a1, b1, d11, 0, 0, 0);

        const int tr0 = w * 32 + h * 4;              // D row base, tile 0
        float be0 = b_edge[n16], be1 = b_edge[16 + n16];
#pragma unroll
        for (int r = 0; r < 4; ++r) {
            hs[tr0 + r][n16]           = f2bf(fmaxf(d00[r] + be0, 0.f));
            hs[tr0 + r][16 + n16]      = f2bf(fmaxf(d01[r] + be1, 0.f));
            hs[tr0 + 16 + r][n16]      = f2bf(fmaxf(d10[r] + be0, 0.f));
            hs[tr0 + 16 + r][16 + n16] = f2bf(fmaxf(d11[r] + be1, 0.f));
        }
    }
    __syncthreads();

    // ---- phase 2: segmented sums from LDS (no search: nstart precomputed) ----
    const int c = lane & 7, sub = lane >> 3;
    const int node0 = nstart[blockIdx.x];

    for (int n = node0 + w; n < N; n += 8) {
        int s0 = off[n];
        if (s0 >= P + BP) break;                     // off monotone -> done
        int e0 = off[n + 1];
        int s = max(s0, P) - P, eEnd = min(e0, P + BP) - P;
        float4 hv = {0.f,0.f,0.f,0.f}, av = {0.f,0.f,0.f,0.f};
        for (int t = s + sub; t < eEnd; t += 8) {
            ushort4 uh = *reinterpret_cast<const ushort4*>(&hs [t][c * 4]);
            ushort4 ua = *reinterpret_cast<const ushort4*>(&asr[t][c * 4]);
            hv.x += bf2f(uh.x); hv.y += bf2f(uh.y); hv.z += bf2f(uh.z); hv.w += bf2f(uh.w);
            av.x += bf2f(ua.x); av.y += bf2f(ua.y); av.z += bf2f(ua.z); av.w += bf2f(ua.w);
        }
#pragma unroll
        for (int m = 8; m < 64; m <<= 1) {
            hv.x += __shfl_xor(hv.x, m); hv.y += __shfl_xor(hv.y, m);
            hv.z += __shfl_xor(hv.z, m); hv.w += __shfl_xor(hv.w, m);
            av.x += __shfl_xor(av.x, m); av.y += __shfl_xor(av.y, m);
            av.z += __shfl_xor(av.z, m); av.w += __shfl_xor(av.w, m);
        }
        if (lane < 8) {
            float* pe = eagg + (size_t)n * 32 + c * 4;
            float* ps = sea  + (size_t)n * 32 + c * 4;
            bool interior = (s0 >= P) && (e0 <= P + BP);
            if (interior) {
                *reinterpret_cast<float4*>(pe) = hv;
                *reinterpret_cast<float4*>(ps) = av;
            } else {
                atomicAdd(pe+0,hv.x); atomicAdd(pe+1,hv.y);
                atomicAdd(pe+2,hv.z); atomicAdd(pe+3,hv.w);
                atomicAdd(ps+0,av.x); atomicAdd(ps+1,av.y);
                atomicAdd(ps+2,av.z); atomicAdd(ps+3,av.w);
            }
        }
    }
}

// out[:,96:128] = dinv * gather-sum(eagg[col]);  copies eagg -> out[:,64:96]
// 2x unrolled: two independent gather chains in flight per lane.
__global__ __launch_bounds__(256) void k_mmagg(
    const int* __restrict__ colsort, const int* __restrict__ off,
    const float* __restrict__ eagg, float* __restrict__ out, int N)
{
    int wid  = (blockIdx.x * blockDim.x + threadIdx.x) >> 6;
    int lane = threadIdx.x & 63;
    if (wid >= N) return;
    int s = off[wid], e = off[wid + 1];
    int c   = lane & 7;
    int sub = lane >> 3;
    float4 acc = {0.f, 0.f, 0.f, 0.f};
    float4 acc2 = {0.f, 0.f, 0.f, 0.f};
    for (int t0 = s; t0 < e; t0 += 16) {
        int t1 = t0 + sub, t2 = t0 + 8 + sub;
        if (t1 < e) {
            float4 v = reinterpret_cast<const float4*>(eagg + (size_t)colsort[t1] * 32)[c];
            acc.x += v.x; acc.y += v.y; acc.z += v.z; acc.w += v.w;
        }
        if (t2 < e) {
            float4 v = reinterpret_cast<const float4*>(eagg + (size_t)colsort[t2] * 32)[c];
            acc2.x += v.x; acc2.y += v.y; acc2.z += v.z; acc2.w += v.w;
        }
    }
    acc.x += acc2.x; acc.y += acc2.y; acc.z += acc2.z; acc.w += acc2.w;
#pragma unroll
    for (int m = 8; m < 64; m <<= 1) {
        acc.x += __shfl_xor(acc.x, m);
        acc.y += __shfl_xor(acc.y, m);
        acc.z += __shfl_xor(acc.z, m);
        acc.w += __shfl_xor(acc.w, m);
    }
    int dg = e - s;
    float dinv = dg > 0 ? rsqrtf((float)dg) : 0.f;
    if (lane < 8) {
        float4 o4 = {acc.x * dinv, acc.y * dinv, acc.z * dinv, acc.w * dinv};
        reinterpret_cast<float4*>(out + (size_t)wid * 224 + 96)[c] = o4;
        float4 eg = reinterpret_cast<const float4*>(eagg + (size_t)wid * 32)[c];
        reinterpret_cast<float4*>(out + (size_t)wid * 224 + 64)[c] = eg;
    }
}

// MFMA node GEMM: block = 4 waves, wave = 16 nodes x 160 outputs, K = 160.
__global__ __launch_bounds__(256) void k_node3(
    const float* __restrict__ x, const float* __restrict__ sea,
    const float* __restrict__ sd, const float* __restrict__ rdeg,
    const unsigned short* __restrict__ Bt,
    const float* __restrict__ b_ego, const float* __restrict__ b_peer,
    float* __restrict__ out, int N)
{
    const int lane = threadIdx.x & 63;
    const int wv   = threadIdx.x >> 6;
    const int wm   = blockIdx.x * 64 + wv * 16;
    const int n16  = lane & 15;
    const int h    = lane >> 4;

    const int m_l = min(wm + n16, N - 1);

    f32x4 acc[10];
#pragma unroll
    for (int f = 0; f < 10; ++f) acc[f] = (f32x4){0.f,0.f,0.f,0.f};

#pragma unroll
    for (int kc = 0; kc < 5; ++kc) {
        bf16x8 bfr[10];
#pragma unroll
        for (int f = 0; f < 10; ++f)
            bfr[f] = ld_bfrag(Bt + (size_t)(f * 16 + n16) * 160 + kc * 32 + h * 4);
        float4 lo, hi;
        if (kc < 4) {
            const float* ap = x + (size_t)m_l * 128 + kc * 32 + h * 4;
            lo = *reinterpret_cast<const float4*>(ap);
            hi = *reinterpret_cast<const float4*>(ap + 16);
        } else {
            float r = rdeg[m_l];
            const float* ap = sea + (size_t)m_l * 32 + h * 4;
            lo = *reinterpret_cast<const float4*>(ap);
            hi = *reinterpret_cast<const float4*>(ap + 16);
            lo.x*=r; lo.y*=r; lo.z*=r; lo.w*=r;
            hi.x*=r; hi.y*=r; hi.z*=r; hi.w*=r;
        }
        bf16x8 a = pack8(lo, hi);
#pragma unroll
        for (int f = 0; f < 10; ++f)
            acc[f] = __builtin_amdgcn_mfma_f32_16x16x32_bf16(a, bfr[f], acc[f], 0, 0, 0);
    }

    const int r4 = h * 4;
    float sdv[4];
#pragma unroll
    for (int r = 0; r < 4; ++r) {
        int node = wm + r4 + r;
        sdv[r] = (node < N) ? sd[node] : 0.f;
    }
#pragma unroll
    for (int f = 0; f < 10; ++f) {
        int c = f * 16 + n16;
        float be = (c < 64)  ? b_ego[c] : 0.f;
        float bp = (c >= 64) ? b_peer[c - 64] : 0.f;
#pragma unroll
        for (int r = 0; r < 4; ++r) {
            int node = wm + r4 + r;
            if (node >= N) continue;
            float v = acc[f][r];
            if (c < 64)
                out[(size_t)node * 224 + c] = fmaxf(v + be, 0.f);
            else
                out[(size_t)node * 224 + 64 + c] = fmaxf(sdv[r] * (v + bp), 0.f);
        }
    }
}

extern "C" void kernel_launch(void* const* d_in, const int* in_sizes, int n_in,
                              void* d_out, int out_size, void* d_ws, size_t ws_size,
                              hipStream_t stream)
{
    const float* x      = (const float*)d_in[0];
    const float* ea     = (const float*)d_in[1];
    const float* W_peer = (const float*)d_in[2];
    const float* b_peer = (const float*)d_in[3];
    const float* W_ego  = (const float*)d_in[4];
    const float* b_ego  = (const float*)d_in[5];
    const float* W_edge = (const float*)d_in[6];
    const float* b_edge = (const float*)d_in[7];
    const int*   ei     = (const int*)d_in[8];

    const int N = in_sizes[0] / 128;
    const int E = in_sizes[8] / 2;
    const int* col = ei;
    const int* row = ei + E;
    const int nblocks = (E + BP - 1) / BP;

    int*   deg_i   = (int*)d_ws;
    float* eagg    = (float*)(deg_i + N);
    float* sea     = eagg + (size_t)32 * N;
    int*   off     = (int*)(sea + (size_t)32 * N);
    int*   cursor  = off + (N + 1);
    int*   bsum    = cursor + N;
    int*   boff    = bsum + 64;
    int*   eids    = boff + 64;
    int*   colsort = eids + E;
    float* sd      = (float*)(colsort + E);
    float* rdeg    = sd + N;
    int*   nstart  = (int*)(rdeg + N);                       // [nblocks]
    unsigned short* Bt  = (unsigned short*)(nstart + nblocks); // 160*160
    unsigned short* Bte = Bt + 160 * 160;                    // 32*32
    float* out     = (float*)d_out;

    hipMemsetAsync(d_ws, 0, (size_t)(65 * N) * sizeof(int), stream);

    const int TB = 256;
    const int NB = (N + 1023) / 1024;
    k_hist        <<<(E + TB - 1) / TB, TB, 0, stream>>>(row, deg_i, E);
    k_prepw       <<<(160*160 + 32*32 + TB - 1) / TB, TB, 0, stream>>>(W_ego, W_peer, W_edge, Bt, Bte);
    k_scan_partial<<<NB, TB, 0, stream>>>(deg_i, bsum, N);
    k_scan_mid    <<<1, 64, 0, stream>>>(bsum, boff, off, NB, N);
    k_scan_final  <<<NB, TB, 0, stream>>>(deg_i, boff, off, cursor, N);
    k_prepsd      <<<(N + TB - 1) / TB, TB, 0, stream>>>(off, sd, rdeg, nstart, N);
    k_scatter     <<<(E + TB - 1) / TB, TB, 0, stream>>>(row, col, cursor, eids, colsort, E);

    k_fused<<<nblocks, 512, 0, stream>>>(ea, eids, off, nstart, Bte, b_edge,
                                         eagg, sea, N, E);

    const int agg_grid = (N + 3) / 4;
    k_mmagg<<<agg_grid, TB, 0, stream>>>(colsort, off, eagg, out, N);
    k_node3<<<(N + 63) / 64, TB, 0, stream>>>(x, sea, sd, rdeg, Bt,
                                              b_ego, b_peer, out, N);
}

// Round 9
// 212.460 us; speedup vs baseline: 20.3458x; 1.0138x over previous
//
#include <hip/hip_runtime.h>

// ---------------------------------------------------------------------------
// CSR build (1 int atomic/edge, int2-merged payload); fused MFMA edge-GEMV +
// segmented aggregation (2 edges/thread, bf16 LDS tiles, nstart precomputed);
// MFMA bf16 node GEMM. No bulk memset: deg zeroed by tiny kernel; eagg/sea
// zeroed only for boundary-crossing / empty nodes inside scan_final.
//   out[:,  0: 64] = relu(x @ W_ego.T + b_ego)
//   out[:, 64: 96] = eagg[i]  = sum_{e:row=i} relu(ea[e] @ W_edge.T + b_edge)
//   out[:, 96:128] = dinv[i] * sum_{e:row=i} eagg[col[e]]
//   out[:,128:224] = relu( sd * (W_peer @ [x | sea/deg] + b_peer) )
// MFMA fragment maps: A/B k-order cancels (same map both sides); C/D layout
// (HW-verified): col = lane&15, row = (lane>>4)*4 + reg.
// ---------------------------------------------------------------------------

typedef float f32x4 __attribute__((ext_vector_type(4)));
typedef short bf16x8 __attribute__((ext_vector_type(8)));

#define BP 256   // CSR positions per k_fused block (512 threads, 2 edges/thread)

__device__ __forceinline__ unsigned short f2bf(float f) {
    unsigned u = __float_as_uint(f);
    u += 0x7fffu + ((u >> 16) & 1u);      // RNE
    return (unsigned short)(u >> 16);
}
__device__ __forceinline__ float bf2f(unsigned short u) {
    return __uint_as_float((unsigned)u << 16);
}
__device__ __forceinline__ ushort4 pk4(float4 v) {
    return (ushort4){f2bf(v.x), f2bf(v.y), f2bf(v.z), f2bf(v.w)};
}
__device__ __forceinline__ bf16x8 pack8(float4 lo, float4 hi) {
    bf16x8 r;
    r[0]=(short)f2bf(lo.x); r[1]=(short)f2bf(lo.y); r[2]=(short)f2bf(lo.z); r[3]=(short)f2bf(lo.w);
    r[4]=(short)f2bf(hi.x); r[5]=(short)f2bf(hi.y); r[6]=(short)f2bf(hi.z); r[7]=(short)f2bf(hi.w);
    return r;
}
__device__ __forceinline__ bf16x8 ld_bfrag(const unsigned short* bp) {
    ushort4 lo = *reinterpret_cast<const ushort4*>(bp);
    ushort4 hi = *reinterpret_cast<const ushort4*>(bp + 16);
    bf16x8 b;
    b[0]=(short)lo.x; b[1]=(short)lo.y; b[2]=(short)lo.z; b[3]=(short)lo.w;
    b[4]=(short)hi.x; b[5]=(short)hi.y; b[6]=(short)hi.z; b[7]=(short)hi.w;
    return b;
}

__global__ __launch_bounds__(256) void k_zero(int* __restrict__ deg, int N) {
    int i = blockIdx.x * blockDim.x + threadIdx.x;
    if (i < N) deg[i] = 0;
}

__global__ __launch_bounds__(256) void k_hist(const int* __restrict__ row,
                                              int* __restrict__ deg, int E) {
    int e = blockIdx.x * blockDim.x + threadIdx.x;
    if (e < E) atomicAdd(&deg[row[e]], 1);
}

__global__ __launch_bounds__(256) void k_scan_partial(const int* __restrict__ deg,
                                                      int* __restrict__ bsum, int N) {
    __shared__ int sh[256];
    int base = blockIdx.x * 1024 + threadIdx.x * 4;
    int s = 0;
#pragma unroll
    for (int q = 0; q < 4; ++q) { int i = base + q; if (i < N) s += deg[i]; }
    sh[threadIdx.x] = s;
    __syncthreads();
    for (int off = 128; off > 0; off >>= 1) {
        if (threadIdx.x < off) sh[threadIdx.x] += sh[threadIdx.x + off];
        __syncthreads();
    }
    if (threadIdx.x == 0) bsum[blockIdx.x] = sh[0];
}

__global__ void k_scan_mid(const int* __restrict__ bsum, int* __restrict__ boff,
                           int* __restrict__ off, int NB, int N) {
    if (threadIdx.x == 0 && blockIdx.x == 0) {
        int acc = 0;
        for (int b = 0; b < NB; ++b) { boff[b] = acc; acc += bsum[b]; }
        off[N] = acc;
    }
}

// scan-final + per-node prep: off/cursor/sd/rdeg/nstart, and zero eagg/sea
// rows ONLY for boundary-crossing or empty nodes (atomicAdd targets).
__global__ __launch_bounds__(256) void k_scan_final(
    const int* __restrict__ deg, const int* __restrict__ boff,
    int* __restrict__ off, int* __restrict__ cursor,
    float* __restrict__ sd, float* __restrict__ rdeg, int* __restrict__ nstart,
    float* __restrict__ eagg, float* __restrict__ sea, int N)
{
    __shared__ int sh[256];
    int t = threadIdx.x;
    int base = blockIdx.x * 1024 + t * 4;
    int v[4];
#pragma unroll
    for (int q = 0; q < 4; ++q) v[q] = (base + q < N) ? deg[base + q] : 0;
    int ts = v[0] + v[1] + v[2] + v[3];
    sh[t] = ts;
    __syncthreads();
    int incl = ts;
    for (int d = 1; d < 256; d <<= 1) {
        int val = (t >= d) ? sh[t - d] : 0;
        __syncthreads();
        incl += val;
        sh[t] = incl;
        __syncthreads();
    }
    int running = boff[blockIdx.x] + incl - ts;
#pragma unroll
    for (int q = 0; q < 4; ++q) {
        int i = base + q;
        if (i < N) {
            int s = running, e = running + v[q];
            off[i] = s; cursor[i] = s;
            int dg = v[q];
            sd[i]   = dg > 0 ? sqrtf((float)dg) : 0.f;
            rdeg[i] = dg > 0 ? 1.f / (float)dg : 0.f;
            for (int b = (s + BP - 1) / BP; b * BP < e; ++b) nstart[b] = i;
            bool zneed = (dg == 0) || ((s / BP) != ((e - 1) / BP));
            if (zneed) {
                float4 z = {0.f, 0.f, 0.f, 0.f};
                float4* pe = reinterpret_cast<float4*>(eagg + (size_t)i * 32);
                float4* ps = reinterpret_cast<float4*>(sea  + (size_t)i * 32);
#pragma unroll
                for (int q2 = 0; q2 < 8; ++q2) { pe[q2] = z; ps[q2] = z; }
            }
            running = e;
        }
    }
}

// scatter edge id + col together: one 8B random write per edge.
__global__ __launch_bounds__(256) void k_scatter(const int* __restrict__ row,
                                                 const int* __restrict__ col,
                                                 int* __restrict__ cursor,
                                                 int2* __restrict__ edat, int E) {
    int e = blockIdx.x * blockDim.x + threadIdx.x;
    if (e >= E) return;
    int pos = atomicAdd(&cursor[row[e]], 1);
    edat[pos] = make_int2(e, col[e]);
}

// Bt[n][k] (bf16,160x160) for node GEMM + Bte[j][k] (bf16,32x32) for edge GEMV
__global__ __launch_bounds__(256) void k_prepw(const float* __restrict__ W_ego,
                                               const float* __restrict__ W_peer,
                                               const float* __restrict__ W_edge,
                                               unsigned short* __restrict__ Bt,
                                               unsigned short* __restrict__ Bte) {
    int idx = blockIdx.x * blockDim.x + threadIdx.x;
    if (idx < 160 * 160) {
        int n = idx / 160, k = idx % 160;
        float v;
        if (n < 64) v = (k < 128) ? W_ego[n * 128 + k] : 0.f;
        else        v = W_peer[(n - 64) * 160 + k];
        Bt[idx] = f2bf(v);
    } else if (idx < 160 * 160 + 32 * 32) {
        int j = idx - 160 * 160;
        Bte[j] = f2bf(W_edge[j]);
    }
}

// Fused: MFMA edge GEMV (2 edges/thread) -> bf16 LDS -> segmented sum.
// 512 threads = 8 waves; 32 edges/wave; BP=256 CSR positions/block.
__global__ __launch_bounds__(512) void k_fused(
    const float* __restrict__ ea, const int2* __restrict__ edat,
    const int* __restrict__ off, const int* __restrict__ nstart,
    const unsigned short* __restrict__ Bte, const float* __restrict__ b_edge,
    float* __restrict__ eagg, float* __restrict__ sea, int N, int E)
{
    __shared__ unsigned short hs [BP][36];   // relu(h_e), bf16
    __shared__ unsigned short asr[BP][36];   // raw ea,    bf16
    const int tid  = threadIdx.x;
    const int w    = tid >> 6;
    const int lane = tid & 63;
    const int n16  = lane & 15;
    const int h    = lane >> 4;
    const int P    = blockIdx.x * BP;

    // ---- phase 1: gather 2 ea rows + 2 MFMA GEMV tiles per wave-pair ----
    {
        const int tA = w * 32 + n16;                 // block-local CSR pos (tile 0)
        const int p0 = min(P + tA,      E - 1);
        const int p1 = min(P + tA + 16, E - 1);
        const int e0i = edat[p0].x;
        const int e1i = edat[p1].x;
        const float* ap0 = ea + (size_t)e0i * 32 + h * 4;
        const float* ap1 = ea + (size_t)e1i * 32 + h * 4;
        float4 lo0 = *reinterpret_cast<const float4*>(ap0);
        float4 hi0 = *reinterpret_cast<const float4*>(ap0 + 16);
        float4 lo1 = *reinterpret_cast<const float4*>(ap1);
        float4 hi1 = *reinterpret_cast<const float4*>(ap1 + 16);

        *reinterpret_cast<ushort4*>(&asr[tA][h * 4])           = pk4(lo0);
        *reinterpret_cast<ushort4*>(&asr[tA][16 + h * 4])      = pk4(hi0);
        *reinterpret_cast<ushort4*>(&asr[tA + 16][h * 4])      = pk4(lo1);
        *reinterpret_cast<ushort4*>(&asr[tA + 16][16 + h * 4]) = pk4(hi1);

        bf16x8 a0 = pack8(lo0, hi0);
        bf16x8 a1 = pack8(lo1, hi1);
        bf16x8 b0 = ld_bfrag(Bte + (size_t)n16 * 32 + h * 4);
        bf16x8 b1 = ld_bfrag(Bte + (size_t)(16 + n16) * 32 + h * 4);
        f32x4 d00 = {0.f,0.f,0.f,0.f}, d01 = {0.f,0.f,0.f,0.f};
        f32x4 d10 = {0.f,0.f,0.f,0.f}, d11 = {0.f,0.f,0.f,0.f};
        d00 = __builtin_amdgcn_mfma_f32_16x16x32_bf16(a0, b0, d00, 0, 0, 0);
        d01 = __builtin_amdgcn_mfma_f32_16x16x32_bf16(a0, b1, d01, 0, 0, 0);
        d10 = __builtin_amdgcn_mfma_f32_16x16x32_bf16(a1, b0, d10, 0, 0, 0);
        d11 = __builtin_amdgcn_mfma_f32_16x16x32_bf16(a1, b1, d11, 0, 0, 0);

        const int tr0 = w * 32 + h * 4;              // D row base, tile 0
        float be0 = b_edge[n16], be1 = b_edge[16 + n16];
#pragma unroll
        for (int r = 0; r < 4; ++r) {
            hs[tr0 + r][n16]           = f2bf(fmaxf(d00[r] + be0, 0.f));
            hs[tr0 + r][16 + n16]      = f2bf(fmaxf(d01[r] + be1, 0.f));
            hs[tr0 + 16 + r][n16]      = f2bf(fmaxf(d10[r] + be0, 0.f));
            hs[tr0 + 16 + r][16 + n16] = f2bf(fmaxf(d11[r] + be1, 0.f));
        }
    }
    __syncthreads();

    // ---- phase 2: segmented sums from LDS (no search: nstart precomputed) ----
    const int c = lane & 7, sub = lane >> 3;
    const int node0 = nstart[blockIdx.x];

    for (int n = node0 + w; n < N; n += 8) {
        int s0 = off[n];
        if (s0 >= P + BP) break;                     // off monotone -> done
        int e0 = off[n + 1];
        int s = max(s0, P) - P, eEnd = min(e0, P + BP) - P;
        float4 hv = {0.f,0.f,0.f,0.f}, av = {0.f,0.f,0.f,0.f};
        for (int t = s + sub; t < eEnd; t += 8) {
            ushort4 uh = *reinterpret_cast<const ushort4*>(&hs [t][c * 4]);
            ushort4 ua = *reinterpret_cast<const ushort4*>(&asr[t][c * 4]);
            hv.x += bf2f(uh.x); hv.y += bf2f(uh.y); hv.z += bf2f(uh.z); hv.w += bf2f(uh.w);
            av.x += bf2f(ua.x); av.y += bf2f(ua.y); av.z += bf2f(ua.z); av.w += bf2f(ua.w);
        }
#pragma unroll
        for (int m = 8; m < 64; m <<= 1) {
            hv.x += __shfl_xor(hv.x, m); hv.y += __shfl_xor(hv.y, m);
            hv.z += __shfl_xor(hv.z, m); hv.w += __shfl_xor(hv.w, m);
            av.x += __shfl_xor(av.x, m); av.y += __shfl_xor(av.y, m);
            av.z += __shfl_xor(av.z, m); av.w += __shfl_xor(av.w, m);
        }
        if (lane < 8) {
            float* pe = eagg + (size_t)n * 32 + c * 4;
            float* ps = sea  + (size_t)n * 32 + c * 4;
            bool interior = (s0 >= P) && (e0 <= P + BP);
            if (interior) {
                *reinterpret_cast<float4*>(pe) = hv;
                *reinterpret_cast<float4*>(ps) = av;
            } else {
                atomicAdd(pe+0,hv.x); atomicAdd(pe+1,hv.y);
                atomicAdd(pe+2,hv.z); atomicAdd(pe+3,hv.w);
                atomicAdd(ps+0,av.x); atomicAdd(ps+1,av.y);
                atomicAdd(ps+2,av.z); atomicAdd(ps+3,av.w);
            }
        }
    }
}

// out[:,96:128] = dinv * gather-sum(eagg[col]);  copies eagg -> out[:,64:96]
// 2x unrolled: two independent gather chains in flight per lane.
__global__ __launch_bounds__(256) void k_mmagg(
    const int2* __restrict__ edat, const int* __restrict__ off,
    const float* __restrict__ eagg, float* __restrict__ out, int N)
{
    int wid  = (blockIdx.x * blockDim.x + threadIdx.x) >> 6;
    int lane = threadIdx.x & 63;
    if (wid >= N) return;
    int s = off[wid], e = off[wid + 1];
    int c   = lane & 7;
    int sub = lane >> 3;
    float4 acc = {0.f, 0.f, 0.f, 0.f};
    float4 acc2 = {0.f, 0.f, 0.f, 0.f};
    for (int t0 = s; t0 < e; t0 += 16) {
        int t1 = t0 + sub, t2 = t0 + 8 + sub;
        if (t1 < e) {
            float4 v = reinterpret_cast<const float4*>(eagg + (size_t)edat[t1].y * 32)[c];
            acc.x += v.x; acc.y += v.y; acc.z += v.z; acc.w += v.w;
        }
        if (t2 < e) {
            float4 v = reinterpret_cast<const float4*>(eagg + (size_t)edat[t2].y * 32)[c];
            acc2.x += v.x; acc2.y += v.y; acc2.z += v.z; acc2.w += v.w;
        }
    }
    acc.x += acc2.x; acc.y += acc2.y; acc.z += acc2.z; acc.w += acc2.w;
#pragma unroll
    for (int m = 8; m < 64; m <<= 1) {
        acc.x += __shfl_xor(acc.x, m);
        acc.y += __shfl_xor(acc.y, m);
        acc.z += __shfl_xor(acc.z, m);
        acc.w += __shfl_xor(acc.w, m);
    }
    int dg = e - s;
    float dinv = dg > 0 ? rsqrtf((float)dg) : 0.f;
    if (lane < 8) {
        float4 o4 = {acc.x * dinv, acc.y * dinv, acc.z * dinv, acc.w * dinv};
        reinterpret_cast<float4*>(out + (size_t)wid * 224 + 96)[c] = o4;
        float4 eg = reinterpret_cast<const float4*>(eagg + (size_t)wid * 32)[c];
        reinterpret_cast<float4*>(out + (size_t)wid * 224 + 64)[c] = eg;
    }
}

// MFMA node GEMM: block = 4 waves, wave = 16 nodes x 160 outputs, K = 160.
__global__ __launch_bounds__(256) void k_node3(
    const float* __restrict__ x, const float* __restrict__ sea,
    const float* __restrict__ sd, const float* __restrict__ rdeg,
    const unsigned short* __restrict__ Bt,
    const float* __restrict__ b_ego, const float* __restrict__ b_peer,
    float* __restrict__ out, int N)
{
    const int lane = threadIdx.x & 63;
    const int wv   = threadIdx.x >> 6;
    const int wm   = blockIdx.x * 64 + wv * 16;
    const int n16  = lane & 15;
    const int h    = lane >> 4;

    const int m_l = min(wm + n16, N - 1);

    f32x4 acc[10];
#pragma unroll
    for (int f = 0; f < 10; ++f) acc[f] = (f32x4){0.f,0.f,0.f,0.f};

#pragma unroll
    for (int kc = 0; kc < 5; ++kc) {
        bf16x8 bfr[10];
#pragma unroll
        for (int f = 0; f < 10; ++f)
            bfr[f] = ld_bfrag(Bt + (size_t)(f * 16 + n16) * 160 + kc * 32 + h * 4);
        float4 lo, hi;
        if (kc < 4) {
            const float* ap = x + (size_t)m_l * 128 + kc * 32 + h * 4;
            lo = *reinterpret_cast<const float4*>(ap);
            hi = *reinterpret_cast<const float4*>(ap + 16);
        } else {
            float r = rdeg[m_l];
            const float* ap = sea + (size_t)m_l * 32 + h * 4;
            lo = *reinterpret_cast<const float4*>(ap);
            hi = *reinterpret_cast<const float4*>(ap + 16);
            lo.x*=r; lo.y*=r; lo.z*=r; lo.w*=r;
            hi.x*=r; hi.y*=r; hi.z*=r; hi.w*=r;
        }
        bf16x8 a = pack8(lo, hi);
#pragma unroll
        for (int f = 0; f < 10; ++f)
            acc[f] = __builtin_amdgcn_mfma_f32_16x16x32_bf16(a, bfr[f], acc[f], 0, 0, 0);
    }

    const int r4 = h * 4;
    float sdv[4];
#pragma unroll
    for (int r = 0; r < 4; ++r) {
        int node = wm + r4 + r;
        sdv[r] = (node < N) ? sd[node] : 0.f;
    }
#pragma unroll
    for (int f = 0; f < 10; ++f) {
        int c = f * 16 + n16;
        float be = (c < 64)  ? b_ego[c] : 0.f;
        float bp = (c >= 64) ? b_peer[c - 64] : 0.f;
#pragma unroll
        for (int r = 0; r < 4; ++r) {
            int node = wm + r4 + r;
            if (node >= N) continue;
            float v = acc[f][r];
            if (c < 64)
                out[(size_t)node * 224 + c] = fmaxf(v + be, 0.f);
            else
                out[(size_t)node * 224 + 64 + c] = fmaxf(sdv[r] * (v + bp), 0.f);
        }
    }
}

extern "C" void kernel_launch(void* const* d_in, const int* in_sizes, int n_in,
                              void* d_out, int out_size, void* d_ws, size_t ws_size,
                              hipStream_t stream)
{
    const float* x      = (const float*)d_in[0];
    const float* ea     = (const float*)d_in[1];
    const float* W_peer = (const float*)d_in[2];
    const float* b_peer = (const float*)d_in[3];
    const float* W_ego  = (const float*)d_in[4];
    const float* b_ego  = (const float*)d_in[5];
    const float* W_edge = (const float*)d_in[6];
    const float* b_edge = (const float*)d_in[7];
    const int*   ei     = (const int*)d_in[8];

    const int N = in_sizes[0] / 128;
    const int E = in_sizes[8] / 2;
    const int* col = ei;
    const int* row = ei + E;
    const int nblocks = (E + BP - 1) / BP;

    // ws layout: [edat int2 E][deg N][eagg 32N][sea 32N][off N+1][cursor N]
    //            [bsum 64][boff 64][sd N][rdeg N][nstart nblocks][Bt][Bte]
    int2*  edat    = (int2*)d_ws;
    int*   deg_i   = (int*)(edat + E);
    float* eagg    = (float*)(deg_i + N);     // offset (2E+N)*4 B, 16B-aligned
    float* sea     = eagg + (size_t)32 * N;
    int*   off     = (int*)(sea + (size_t)32 * N);
    int*   cursor  = off + (N + 1);
    int*   bsum    = cursor + N;
    int*   boff    = bsum + 64;
    float* sd      = (float*)(boff + 64);
    float* rdeg    = sd + N;
    int*   nstart  = (int*)(rdeg + N);
    unsigned short* Bt  = (unsigned short*)(nstart + nblocks);  // 160*160
    unsigned short* Bte = Bt + 160 * 160;                       // 32*32
    float* out     = (float*)d_out;

    const int TB = 256;
    const int NB = (N + 1023) / 1024;
    k_zero        <<<(N + TB - 1) / TB, TB, 0, stream>>>(deg_i, N);
    k_prepw       <<<(160*160 + 32*32 + TB - 1) / TB, TB, 0, stream>>>(W_ego, W_peer, W_edge, Bt, Bte);
    k_hist        <<<(E + TB - 1) / TB, TB, 0, stream>>>(row, deg_i, E);
    k_scan_partial<<<NB, TB, 0, stream>>>(deg_i, bsum, N);
    k_scan_mid    <<<1, 64, 0, stream>>>(bsum, boff, off, NB, N);
    k_scan_final  <<<NB, TB, 0, stream>>>(deg_i, boff, off, cursor, sd, rdeg,
                                          nstart, eagg, sea, N);
    k_scatter     <<<(E + TB - 1) / TB, TB, 0, stream>>>(row, col, cursor, edat, E);

    k_fused<<<nblocks, 512, 0, stream>>>(ea, edat, off, nstart, Bte, b_edge,
                                         eagg, sea, N, E);

    const int agg_grid = (N + 3) / 4;
    k_mmagg<<<agg_grid, TB, 0, stream>>>(edat, off, eagg, out, N);
    k_node3<<<(N + 63) / 64, TB, 0, stream>>>(x, sea, sd, rdeg, Bt,
                                              b_ego, b_peer, out, N);
}

// Round 10
// 202.880 us; speedup vs baseline: 21.3065x; 1.0472x over previous
//
#include <hip/hip_runtime.h>

// ---------------------------------------------------------------------------
// Pipeline (all heavy memory ops streaming or full-line random writes):
//   k_hist:    deg histogram + per-edge rank (1 int atomic/edge)
//   scans:     off = exclusive_scan(deg); sd/rdeg/nstart; zero boundary rows
//   k_scatcvt: ea (streaming read) -> bf16 -> easorted[off[row]+rank] (64B
//              full-line random write) + colsort[pos]
//   k_agg:     streaming easorted -> MFMA edge GEMV -> LDS -> segmented sums
//   k_mmagg:   out[:,96:128] = dinv * gather-sum(eagg[colsort]); copy eagg
//   k_node3:   MFMA bf16 node GEMM -> out[:,0:64] and out[:,128:224]
// Math:
//   out[:,  0: 64] = relu(x @ W_ego.T + b_ego)
//   out[:, 64: 96] = eagg[i]  = sum_{e:row=i} relu(ea[e] @ W_edge.T + b_edge)
//   out[:, 96:128] = dinv[i] * sum_{e:row=i} eagg[col[e]]
//   out[:,128:224] = relu( sd * (W_peer @ [x | sea/deg] + b_peer) )
// MFMA fragment maps: A/B k-order cancels (same map both sides); C/D layout
// (HW-verified): col = lane&15, row = (lane>>4)*4 + reg.
// ---------------------------------------------------------------------------

typedef float f32x4 __attribute__((ext_vector_type(4)));
typedef short bf16x8 __attribute__((ext_vector_type(8)));
typedef unsigned short u16x8 __attribute__((ext_vector_type(8)));

#define BP 256   // CSR positions per k_agg block (512 threads, 2 edges/thread)

__device__ __forceinline__ unsigned short f2bf(float f) {
    unsigned u = __float_as_uint(f);
    u += 0x7fffu + ((u >> 16) & 1u);      // RNE
    return (unsigned short)(u >> 16);
}
__device__ __forceinline__ float bf2f(unsigned short u) {
    return __uint_as_float((unsigned)u << 16);
}
__device__ __forceinline__ u16x8 pk8u(float4 lo, float4 hi) {
    u16x8 r;
    r[0]=f2bf(lo.x); r[1]=f2bf(lo.y); r[2]=f2bf(lo.z); r[3]=f2bf(lo.w);
    r[4]=f2bf(hi.x); r[5]=f2bf(hi.y); r[6]=f2bf(hi.z); r[7]=f2bf(hi.w);
    return r;
}
__device__ __forceinline__ bf16x8 mk_frag(ushort4 lo, ushort4 hi) {
    bf16x8 b;
    b[0]=(short)lo.x; b[1]=(short)lo.y; b[2]=(short)lo.z; b[3]=(short)lo.w;
    b[4]=(short)hi.x; b[5]=(short)hi.y; b[6]=(short)hi.z; b[7]=(short)hi.w;
    return b;
}
__device__ __forceinline__ bf16x8 ld_bfrag(const unsigned short* bp) {
    return mk_frag(*reinterpret_cast<const ushort4*>(bp),
                   *reinterpret_cast<const ushort4*>(bp + 16));
}

__global__ __launch_bounds__(256) void k_zero(int* __restrict__ deg, int N) {
    int i = blockIdx.x * blockDim.x + threadIdx.x;
    if (i < N) deg[i] = 0;
}

// histogram + per-edge rank within its node
__global__ __launch_bounds__(256) void k_hist(const int* __restrict__ row,
                                              int* __restrict__ deg,
                                              int* __restrict__ rank, int E) {
    int e = blockIdx.x * blockDim.x + threadIdx.x;
    if (e < E) rank[e] = atomicAdd(&deg[row[e]], 1);
}

__global__ __launch_bounds__(256) void k_scan_partial(const int* __restrict__ deg,
                                                      int* __restrict__ bsum, int N) {
    __shared__ int sh[256];
    int base = blockIdx.x * 1024 + threadIdx.x * 4;
    int s = 0;
#pragma unroll
    for (int q = 0; q < 4; ++q) { int i = base + q; if (i < N) s += deg[i]; }
    sh[threadIdx.x] = s;
    __syncthreads();
    for (int off = 128; off > 0; off >>= 1) {
        if (threadIdx.x < off) sh[threadIdx.x] += sh[threadIdx.x + off];
        __syncthreads();
    }
    if (threadIdx.x == 0) bsum[blockIdx.x] = sh[0];
}

__global__ void k_scan_mid(const int* __restrict__ bsum, int* __restrict__ boff,
                           int* __restrict__ off, int NB, int N) {
    if (threadIdx.x == 0 && blockIdx.x == 0) {
        int acc = 0;
        for (int b = 0; b < NB; ++b) { boff[b] = acc; acc += bsum[b]; }
        off[N] = acc;
    }
}

// scan-final + per-node prep: off/sd/rdeg/nstart; zero eagg/sea rows ONLY for
// boundary-crossing or empty nodes (the atomicAdd targets in k_agg).
__global__ __launch_bounds__(256) void k_scan_final(
    const int* __restrict__ deg, const int* __restrict__ boff,
    int* __restrict__ off,
    float* __restrict__ sd, float* __restrict__ rdeg, int* __restrict__ nstart,
    float* __restrict__ eagg, float* __restrict__ sea, int N)
{
    __shared__ int sh[256];
    int t = threadIdx.x;
    int base = blockIdx.x * 1024 + t * 4;
    int v[4];
#pragma unroll
    for (int q = 0; q < 4; ++q) v[q] = (base + q < N) ? deg[base + q] : 0;
    int ts = v[0] + v[1] + v[2] + v[3];
    sh[t] = ts;
    __syncthreads();
    int incl = ts;
    for (int d = 1; d < 256; d <<= 1) {
        int val = (t >= d) ? sh[t - d] : 0;
        __syncthreads();
        incl += val;
        sh[t] = incl;
        __syncthreads();
    }
    int running = boff[blockIdx.x] + incl - ts;
#pragma unroll
    for (int q = 0; q < 4; ++q) {
        int i = base + q;
        if (i < N) {
            int s = running, e = running + v[q];
            off[i] = s;
            int dg = v[q];
            sd[i]   = dg > 0 ? sqrtf((float)dg) : 0.f;
            rdeg[i] = dg > 0 ? 1.f / (float)dg : 0.f;
            for (int b = (s + BP - 1) / BP; b * BP < e; ++b) nstart[b] = i;
            bool zneed = (dg == 0) || ((s / BP) != ((e - 1) / BP));
            if (zneed) {
                float4 z = {0.f, 0.f, 0.f, 0.f};
                float4* pe = reinterpret_cast<float4*>(eagg + (size_t)i * 32);
                float4* ps = reinterpret_cast<float4*>(sea  + (size_t)i * 32);
#pragma unroll
                for (int q2 = 0; q2 < 8; ++q2) { pe[q2] = z; ps[q2] = z; }
            }
            running = e;
        }
    }
}

// streaming ea read -> bf16 -> full-line (64B) random write at CSR position
__global__ __launch_bounds__(256) void k_scatcvt(
    const float* __restrict__ ea, const int* __restrict__ row,
    const int* __restrict__ col, const int* __restrict__ off,
    const int* __restrict__ rank,
    unsigned short* __restrict__ easorted, int* __restrict__ colsort, int E)
{
    int e = blockIdx.x * blockDim.x + threadIdx.x;
    if (e >= E) return;
    int pos = off[row[e]] + rank[e];
    const float4* src = reinterpret_cast<const float4*>(ea + (size_t)e * 32);
    u16x8* dst = reinterpret_cast<u16x8*>(easorted + (size_t)pos * 32);
#pragma unroll
    for (int q = 0; q < 4; ++q)
        dst[q] = pk8u(src[2 * q], src[2 * q + 1]);
    colsort[pos] = col[e];
}

// Bt[n][k] (bf16,160x160) for node GEMM + Bte[j][k] (bf16,32x32) for edge GEMV
__global__ __launch_bounds__(256) void k_prepw(const float* __restrict__ W_ego,
                                               const float* __restrict__ W_peer,
                                               const float* __restrict__ W_edge,
                                               unsigned short* __restrict__ Bt,
                                               unsigned short* __restrict__ Bte) {
    int idx = blockIdx.x * blockDim.x + threadIdx.x;
    if (idx < 160 * 160) {
        int n = idx / 160, k = idx % 160;
        float v;
        if (n < 64) v = (k < 128) ? W_ego[n * 128 + k] : 0.f;
        else        v = W_peer[(n - 64) * 160 + k];
        Bt[idx] = f2bf(v);
    } else if (idx < 160 * 160 + 32 * 32) {
        int j = idx - 160 * 160;
        Bte[j] = f2bf(W_edge[j]);
    }
}

// Streaming sorted records -> MFMA edge GEMV -> bf16 LDS -> segmented sum.
// 512 threads = 8 waves; 32 edges/wave; BP=256 CSR positions/block.
__global__ __launch_bounds__(512) void k_agg(
    const unsigned short* __restrict__ easorted,
    const int* __restrict__ off, const int* __restrict__ nstart,
    const unsigned short* __restrict__ Bte, const float* __restrict__ b_edge,
    float* __restrict__ eagg, float* __restrict__ sea, int N, int E)
{
    __shared__ unsigned short hs [BP][36];   // relu(h_e), bf16
    __shared__ unsigned short asr[BP][36];   // raw ea,    bf16
    const int tid  = threadIdx.x;
    const int w    = tid >> 6;
    const int lane = tid & 63;
    const int n16  = lane & 15;
    const int h    = lane >> 4;
    const int P    = blockIdx.x * BP;

    // ---- phase 1: streaming record read + MFMA GEMV (2 edges/thread) ----
    {
        const int tA = w * 32 + n16;                 // block-local CSR pos (tile 0)
        const int p0 = min(P + tA,      E - 1);
        const int p1 = min(P + tA + 16, E - 1);
        const unsigned short* r0 = easorted + (size_t)p0 * 32 + h * 4;
        const unsigned short* r1 = easorted + (size_t)p1 * 32 + h * 4;
        ushort4 lo0 = *reinterpret_cast<const ushort4*>(r0);
        ushort4 hi0 = *reinterpret_cast<const ushort4*>(r0 + 16);
        ushort4 lo1 = *reinterpret_cast<const ushort4*>(r1);
        ushort4 hi1 = *reinterpret_cast<const ushort4*>(r1 + 16);

        *reinterpret_cast<ushort4*>(&asr[tA][h * 4])           = lo0;
        *reinterpret_cast<ushort4*>(&asr[tA][16 + h * 4])      = hi0;
        *reinterpret_cast<ushort4*>(&asr[tA + 16][h * 4])      = lo1;
        *reinterpret_cast<ushort4*>(&asr[tA + 16][16 + h * 4]) = hi1;

        bf16x8 a0 = mk_frag(lo0, hi0);
        bf16x8 a1 = mk_frag(lo1, hi1);
        bf16x8 b0 = ld_bfrag(Bte + (size_t)n16 * 32 + h * 4);
        bf16x8 b1 = ld_bfrag(Bte + (size_t)(16 + n16) * 32 + h * 4);
        f32x4 d00 = {0.f,0.f,0.f,0.f}, d01 = {0.f,0.f,0.f,0.f};
        f32x4 d10 = {0.f,0.f,0.f,0.f}, d11 = {0.f,0.f,0.f,0.f};
        d00 = __builtin_amdgcn_mfma_f32_16x16x32_bf16(a0, b0, d00, 0, 0, 0);
        d01 = __builtin_amdgcn_mfma_f32_16x16x32_bf16(a0, b1, d01, 0, 0, 0);
        d10 = __builtin_amdgcn_mfma_f32_16x16x32_bf16(a1, b0, d10, 0, 0, 0);
        d11 = __builtin_amdgcn_mfma_f32_16x16x32_bf16(a1, b1, d11, 0, 0, 0);

        const int tr0 = w * 32 + h * 4;              // D row base = edge
        float be0 = b_edge[n16], be1 = b_edge[16 + n16];
#pragma unroll
        for (int r = 0; r < 4; ++r) {
            hs[tr0 + r][n16]           = f2bf(fmaxf(d00[r] + be0, 0.f));
            hs[tr0 + r][16 + n16]      = f2bf(fmaxf(d01[r] + be1, 0.f));
            hs[tr0 + 16 + r][n16]      = f2bf(fmaxf(d10[r] + be0, 0.f));
            hs[tr0 + 16 + r][16 + n16] = f2bf(fmaxf(d11[r] + be1, 0.f));
        }
    }
    __syncthreads();

    // ---- phase 2: segmented sums from LDS (nstart precomputed) ----
    const int c = lane & 7, sub = lane >> 3;
    const int node0 = nstart[blockIdx.x];

    for (int n = node0 + w; n < N; n += 8) {
        int s0 = off[n];
        if (s0 >= P + BP) break;                     // off monotone -> done
        int e0 = off[n + 1];
        int s = max(s0, P) - P, eEnd = min(e0, P + BP) - P;
        float4 hv = {0.f,0.f,0.f,0.f}, av = {0.f,0.f,0.f,0.f};
        for (int t = s + sub; t < eEnd; t += 8) {
            ushort4 uh = *reinterpret_cast<const ushort4*>(&hs [t][c * 4]);
            ushort4 ua = *reinterpret_cast<const ushort4*>(&asr[t][c * 4]);
            hv.x += bf2f(uh.x); hv.y += bf2f(uh.y); hv.z += bf2f(uh.z); hv.w += bf2f(uh.w);
            av.x += bf2f(ua.x); av.y += bf2f(ua.y); av.z += bf2f(ua.z); av.w += bf2f(ua.w);
        }
#pragma unroll
        for (int m = 8; m < 64; m <<= 1) {
            hv.x += __shfl_xor(hv.x, m); hv.y += __shfl_xor(hv.y, m);
            hv.z += __shfl_xor(hv.z, m); hv.w += __shfl_xor(hv.w, m);
            av.x += __shfl_xor(av.x, m); av.y += __shfl_xor(av.y, m);
            av.z += __shfl_xor(av.z, m); av.w += __shfl_xor(av.w, m);
        }
        if (lane < 8) {
            float* pe = eagg + (size_t)n * 32 + c * 4;
            float* ps = sea  + (size_t)n * 32 + c * 4;
            bool interior = (s0 >= P) && (e0 <= P + BP);
            if (interior) {
                *reinterpret_cast<float4*>(pe) = hv;
                *reinterpret_cast<float4*>(ps) = av;
            } else {
                atomicAdd(pe+0,hv.x); atomicAdd(pe+1,hv.y);
                atomicAdd(pe+2,hv.z); atomicAdd(pe+3,hv.w);
                atomicAdd(ps+0,av.x); atomicAdd(ps+1,av.y);
                atomicAdd(ps+2,av.z); atomicAdd(ps+3,av.w);
            }
        }
    }
}

// out[:,96:128] = dinv * gather-sum(eagg[colsort]);  copies eagg -> out[:,64:96]
__global__ __launch_bounds__(256) void k_mmagg(
    const int* __restrict__ colsort, const int* __restrict__ off,
    const float* __restrict__ eagg, float* __restrict__ out, int N)
{
    int wid  = (blockIdx.x * blockDim.x + threadIdx.x) >> 6;
    int lane = threadIdx.x & 63;
    if (wid >= N) return;
    int s = off[wid], e = off[wid + 1];
    int c   = lane & 7;
    int sub = lane >> 3;
    float4 acc = {0.f, 0.f, 0.f, 0.f};
    float4 acc2 = {0.f, 0.f, 0.f, 0.f};
    for (int t0 = s; t0 < e; t0 += 16) {
        int t1 = t0 + sub, t2 = t0 + 8 + sub;
        if (t1 < e) {
            float4 v = reinterpret_cast<const float4*>(eagg + (size_t)colsort[t1] * 32)[c];
            acc.x += v.x; acc.y += v.y; acc.z += v.z; acc.w += v.w;
        }
        if (t2 < e) {
            float4 v = reinterpret_cast<const float4*>(eagg + (size_t)colsort[t2] * 32)[c];
            acc2.x += v.x; acc2.y += v.y; acc2.z += v.z; acc2.w += v.w;
        }
    }
    acc.x += acc2.x; acc.y += acc2.y; acc.z += acc2.z; acc.w += acc2.w;
#pragma unroll
    for (int m = 8; m < 64; m <<= 1) {
        acc.x += __shfl_xor(acc.x, m);
        acc.y += __shfl_xor(acc.y, m);
        acc.z += __shfl_xor(acc.z, m);
        acc.w += __shfl_xor(acc.w, m);
    }
    int dg = e - s;
    float dinv = dg > 0 ? rsqrtf((float)dg) : 0.f;
    if (lane < 8) {
        float4 o4 = {acc.x * dinv, acc.y * dinv, acc.z * dinv, acc.w * dinv};
        reinterpret_cast<float4*>(out + (size_t)wid * 224 + 96)[c] = o4;
        float4 eg = reinterpret_cast<const float4*>(eagg + (size_t)wid * 32)[c];
        reinterpret_cast<float4*>(out + (size_t)wid * 224 + 64)[c] = eg;
    }
}

// MFMA node GEMM: block = 4 waves, wave = 16 nodes x 160 outputs, K = 160.
__global__ __launch_bounds__(256) void k_node3(
    const float* __restrict__ x, const float* __restrict__ sea,
    const float* __restrict__ sd, const float* __restrict__ rdeg,
    const unsigned short* __restrict__ Bt,
    const float* __restrict__ b_ego, const float* __restrict__ b_peer,
    float* __restrict__ out, int N)
{
    const int lane = threadIdx.x & 63;
    const int wv   = threadIdx.x >> 6;
    const int wm   = blockIdx.x * 64 + wv * 16;
    const int n16  = lane & 15;
    const int h    = lane >> 4;

    const int m_l = min(wm + n16, N - 1);

    f32x4 acc[10];
#pragma unroll
    for (int f = 0; f < 10; ++f) acc[f] = (f32x4){0.f,0.f,0.f,0.f};

#pragma unroll
    for (int kc = 0; kc < 5; ++kc) {
        bf16x8 bfr[10];
#pragma unroll
        for (int f = 0; f < 10; ++f)
            bfr[f] = ld_bfrag(Bt + (size_t)(f * 16 + n16) * 160 + kc * 32 + h * 4);
        float4 lo, hi;
        if (kc < 4) {
            const float* ap = x + (size_t)m_l * 128 + kc * 32 + h * 4;
            lo = *reinterpret_cast<const float4*>(ap);
            hi = *reinterpret_cast<const float4*>(ap + 16);
        } else {
            float r = rdeg[m_l];
            const float* ap = sea + (size_t)m_l * 32 + h * 4;
            lo = *reinterpret_cast<const float4*>(ap);
            hi = *reinterpret_cast<const float4*>(ap + 16);
            lo.x*=r; lo.y*=r; lo.z*=r; lo.w*=r;
            hi.x*=r; hi.y*=r; hi.z*=r; hi.w*=r;
        }
        u16x8 au = pk8u(lo, hi);
        bf16x8 a;
#pragma unroll
        for (int q = 0; q < 8; ++q) a[q] = (short)au[q];
#pragma unroll
        for (int f = 0; f < 10; ++f)
            acc[f] = __builtin_amdgcn_mfma_f32_16x16x32_bf16(a, bfr[f], acc[f], 0, 0, 0);
    }

    const int r4 = h * 4;
    float sdv[4];
#pragma unroll
    for (int r = 0; r < 4; ++r) {
        int node = wm + r4 + r;
        sdv[r] = (node < N) ? sd[node] : 0.f;
    }
#pragma unroll
    for (int f = 0; f < 10; ++f) {
        int c = f * 16 + n16;
        float be = (c < 64)  ? b_ego[c] : 0.f;
        float bp = (c >= 64) ? b_peer[c - 64] : 0.f;
#pragma unroll
        for (int r = 0; r < 4; ++r) {
            int node = wm + r4 + r;
            if (node >= N) continue;
            float v = acc[f][r];
            if (c < 64)
                out[(size_t)node * 224 + c] = fmaxf(v + be, 0.f);
            else
                out[(size_t)node * 224 + 64 + c] = fmaxf(sdv[r] * (v + bp), 0.f);
        }
    }
}

extern "C" void kernel_launch(void* const* d_in, const int* in_sizes, int n_in,
                              void* d_out, int out_size, void* d_ws, size_t ws_size,
                              hipStream_t stream)
{
    const float* x      = (const float*)d_in[0];
    const float* ea     = (const float*)d_in[1];
    const float* W_peer = (const float*)d_in[2];
    const float* b_peer = (const float*)d_in[3];
    const float* W_ego  = (const float*)d_in[4];
    const float* b_ego  = (const float*)d_in[5];
    const float* W_edge = (const float*)d_in[6];
    const float* b_edge = (const float*)d_in[7];
    const int*   ei     = (const int*)d_in[8];

    const int N = in_sizes[0] / 128;
    const int E = in_sizes[8] / 2;
    const int* col = ei;
    const int* row = ei + E;
    const int nblocks = (E + BP - 1) / BP;

    // ws layout: [rank E][easorted 32E u16][colsort E][deg N][eagg 32N][sea 32N]
    //            [off N+1][bsum 64][boff 64][sd N][rdeg N][nstart nblocks][Bt][Bte]
    int*            rank     = (int*)d_ws;
    unsigned short* easorted = (unsigned short*)(rank + E);
    int*            colsort  = (int*)(easorted + (size_t)32 * E);
    int*            deg_i    = colsort + E;
    float*          eagg     = (float*)(deg_i + N);
    float*          sea      = eagg + (size_t)32 * N;
    int*            off      = (int*)(sea + (size_t)32 * N);
    int*            bsum     = off + (N + 1);
    int*            boff     = bsum + 64;
    float*          sd       = (float*)(boff + 64);
    float*          rdeg     = sd + N;
    int*            nstart   = (int*)(rdeg + N);
    unsigned short* Bt       = (unsigned short*)(nstart + nblocks);  // 160*160
    unsigned short* Bte      = Bt + 160 * 160;                       // 32*32
    float*          out      = (float*)d_out;

    const int TB = 256;
    const int NB = (N + 1023) / 1024;
    k_zero        <<<(N + TB - 1) / TB, TB, 0, stream>>>(deg_i, N);
    k_prepw       <<<(160*160 + 32*32 + TB - 1) / TB, TB, 0, stream>>>(W_ego, W_peer, W_edge, Bt, Bte);
    k_hist        <<<(E + TB - 1) / TB, TB, 0, stream>>>(row, deg_i, rank, E);
    k_scan_partial<<<NB, TB, 0, stream>>>(deg_i, bsum, N);
    k_scan_mid    <<<1, 64, 0, stream>>>(bsum, boff, off, NB, N);
    k_scan_final  <<<NB, TB, 0, stream>>>(deg_i, boff, off, sd, rdeg,
                                          nstart, eagg, sea, N);
    k_scatcvt     <<<(E + TB - 1) / TB, TB, 0, stream>>>(ea, row, col, off, rank,
                                                         easorted, colsort, E);

    k_agg<<<nblocks, 512, 0, stream>>>(easorted, off, nstart, Bte, b_edge,
                                       eagg, sea, N, E);

    const int agg_grid = (N + 3) / 4;
    k_mmagg<<<agg_grid, TB, 0, stream>>>(colsort, off, eagg, out, N);
    k_node3<<<(N + 63) / 64, TB, 0, stream>>>(x, sea, sd, rdeg, Bt,
                                              b_ego, b_peer, out, N);
}